// Round 3
// baseline (619.618 us; speedup 1.0000x reference)
//
#include <hip/hip_runtime.h>
#include <hip/hip_cooperative_groups.h>
#include <math.h>

namespace cg = cooperative_groups;

#define FC 256
#define NB 8
#define RS 136   // LDS act row stride in fp16 elems (128 ci + 8 pad)

typedef __attribute__((ext_vector_type(8))) _Float16 f16x8;
typedef __attribute__((ext_vector_type(4))) float f32x4;

__device__ __forceinline__ float lrelu(float v) { return v > 0.f ? v : 0.2f * v; }
__device__ __forceinline__ unsigned short f2h(float f) {
  _Float16 h = (_Float16)f;
  return *(unsigned short*)&h;
}
__device__ __forceinline__ void bar() { asm volatile("s_barrier" ::: "memory"); }
__device__ __forceinline__ void wait_lgkm0() { asm volatile("s_waitcnt lgkmcnt(0)" ::: "memory"); }

// ---------------- weight pack: fp32 -> fp16, MFMA A-fragment layout ----------------
// Encoder layers: per (l,kw,ks,ct): 64 lanes x 8 halves; co = ct*16 + (lane&15),
// ci = ks*32 + (lane>>4)*8 + e. A-load for a wave = one contiguous 1KB burst.
#define N1 344064   // 3*7*128*128   enc w123
#define N2 196608   // 4*3*128*128   enc w4567
#define N3 32768    // 256*128       enc w8 (Ct=16)
#define NTOT 573440
#define NWN 2097152 // 8*512*512     wnet: per (li,k32,rt): row=rt*16+(lane&15), k=k32*32+(lane>>4)*8+e

__global__ void pack_kernel(const float* __restrict__ w123,
                            const float* __restrict__ w4567,
                            const float* __restrict__ w8,
                            const float* __restrict__ mw,
                            const float* __restrict__ gw,
                            unsigned short* __restrict__ wp,
                            unsigned short* __restrict__ wn) {
  int idx = blockIdx.x * 512 + threadIdx.x;
  if (idx < N1) {
    int e = idx & 7, lane = (idx >> 3) & 63, ct = (idx >> 9) & 7, ks = (idx >> 12) & 3, t = idx >> 14;
    int l = t / 7, kw = t % 7;
    int co = ct * 16 + (lane & 15), ci = ks * 32 + (lane >> 4) * 8 + e;
    wp[idx] = f2h(w123[(((l * 128 + co) * 128) + ci) * 7 + kw]);
  } else if (idx < N1 + N2) {
    int k = idx - N1;
    int e = k & 7, lane = (k >> 3) & 63, ct = (k >> 9) & 7, ks = (k >> 12) & 3, t = k >> 14;
    int l = t / 3, kw = t % 3;
    int co = ct * 16 + (lane & 15), ci = ks * 32 + (lane >> 4) * 8 + e;
    wp[idx] = f2h(w4567[(((l * 128 + co) * 128) + ci) * 3 + kw]);
  } else if (idx < NTOT) {
    int k = idx - N1 - N2;
    int e = k & 7, lane = (k >> 3) & 63, ct = (k >> 9) & 15, ks = (k >> 13) & 3;
    int co = ct * 16 + (lane & 15), ci = ks * 32 + (lane >> 4) * 8 + e;
    wp[idx] = f2h(w8[co * 128 + ci]);
  } else if (idx < NTOT + NWN) {
    int k2 = idx - NTOT;
    int li = k2 >> 18, w = k2 & 262143;
    int e = w & 7, lane = (w >> 3) & 63, rt = (w >> 9) & 31, k32 = w >> 14;
    int row = rt * 16 + (lane & 15), k = k32 * 32 + (lane >> 4) * 8 + e;
    int ch = row >> 1, mat = row & 1, kw = k >> 8, ci = k & 255;
    const float* src = mat ? gw : mw;
    wn[k2] = f2h(src[(((size_t)li * 256 + ch) * 256 + ci) * 2 + kw]);
  }
}

// ---------------- direct-load MFMA conv layer (encoder1): no staging, no intra-layer barriers ----
template<int KW, int POFF, int PIN, int POUT, int MC, int MN, int OM>
__device__ __forceinline__ void mlayer_d(const unsigned short* __restrict__ wp,
                                         const unsigned short* __restrict__ sin_,
                                         unsigned short* __restrict__ sout,
                                         unsigned short* __restrict__ gact,
                                         int tid, int frame) {
  constexpr int HRIN = PIN / 2 + 4;
  constexpr int HROUT = POUT / 2 + 4;
  constexpr int Nt = (POUT + 15) / 16;
  constexpr int MNg = Nt / MN;
  constexpr int MCg = 8 / MNg;
  static_assert(MC * MCg == 8, "cout tiling must cover 128 channels");
  constexpr int NS = KW * 4;
  constexpr int DA = NS < 4 ? NS : 4;
  constexpr int DB = NS < 3 ? NS : 3;

  const int wid = tid >> 6, lane = tid & 63, nl = lane & 15, q = lane >> 4;
  const int mcg = wid / MNg, mng = wid % MNg;
  const int ct0 = mcg * MC, nt0 = mng * MN;

  int jj[MN]; bool val[MN]; int rofs[MN][KW];
#pragma unroll
  for (int jn = 0; jn < MN; ++jn) {
    int n = (nt0 + jn) * 16 + nl;
    val[jn] = (n < POUT);
    jj[jn] = val[jn] ? n : 0;
#pragma unroll
    for (int kw = 0; kw < KW; ++kw) {
      int P = 2 * jj[jn] + kw - POFF + 4;
      rofs[jn][kw] = ((P & 1) * HRIN + (P >> 1)) * RS + q * 8;
    }
  }
  const unsigned short* wl = wp + (size_t)ct0 * 512 + lane * 8;

  f32x4 acc[MC][MN];
#pragma unroll
  for (int i = 0; i < MC; ++i)
#pragma unroll
    for (int jn = 0; jn < MN; ++jn) acc[i][jn] = (f32x4){0.f, 0.f, 0.f, 0.f};

  f16x8 A[DA][MC], B[DB][MN];
#pragma unroll
  for (int s = 0; s < DA; ++s)
#pragma unroll
    for (int i = 0; i < MC; ++i)
      A[s][i] = *(const f16x8*)(wl + (size_t)s * 4096 + i * 512);
#pragma unroll
  for (int s = 0; s < DB; ++s) {
    const int kw = s >> 2, ks = s & 3;
#pragma unroll
    for (int jn = 0; jn < MN; ++jn)
      B[s][jn] = *(const f16x8*)(sin_ + rofs[jn][kw] + ks * 32);
  }
#pragma unroll
  for (int s = 0; s < NS; ++s) {
    const int sa = s % DA, sb = s % DB;
#pragma unroll
    for (int i = 0; i < MC; ++i)
#pragma unroll
      for (int jn = 0; jn < MN; ++jn)
        acc[i][jn] = __builtin_amdgcn_mfma_f32_16x16x32_f16(A[sa][i], B[sb][jn], acc[i][jn], 0, 0, 0);
    if (s + DA < NS) {
#pragma unroll
      for (int i = 0; i < MC; ++i)
        A[sa][i] = *(const f16x8*)(wl + (size_t)(s + DA) * 4096 + i * 512);
    }
    if (s + DB < NS) {
      const int kw = (s + DB) >> 2, ks = (s + DB) & 3;
#pragma unroll
      for (int jn = 0; jn < MN; ++jn)
        B[sb][jn] = *(const f16x8*)(sin_ + rofs[jn][kw] + ks * 32);
    }
  }

#pragma unroll
  for (int i = 0; i < MC; ++i) {
#pragma unroll
    for (int jn = 0; jn < MN; ++jn) {
      if (!val[jn]) continue;
      unsigned int lo = (unsigned)f2h(lrelu(acc[i][jn][0])) | ((unsigned)f2h(lrelu(acc[i][jn][1])) << 16);
      unsigned int hi = (unsigned)f2h(lrelu(acc[i][jn][2])) | ((unsigned)f2h(lrelu(acc[i][jn][3])) << 16);
      const int j = jj[jn];
      if (OM == 1) {
        *(uint2*)(gact + ((size_t)frame * POUT + j) * 128 + (ct0 + i) * 16 + q * 4) = make_uint2(lo, hi);
      } else {
        const int row = (j & 1) * HROUT + (j >> 1) + 2;
        *(uint2*)(sout + (size_t)row * RS + (ct0 + i) * 16 + q * 4) = make_uint2(lo, hi);
      }
    }
  }
  if (OM == 0) {
    constexpr int DEND = ((POUT - 1) >> 1) + 3;
    constexpr int NZ = 2 + (HROUT - DEND);
    unsigned int* zp = (unsigned int*)sout;
    for (int s2 = tid; s2 < 2 * NZ * 68; s2 += 512) {
      int col = s2 % 68, rr = s2 / 68;
      int par = rr / NZ, rz = rr % NZ;
      int row = rz < 2 ? rz : DEND + rz - 2;
      zp[((size_t)par * HROUT + row) * 68 + col] = 0;
    }
    __syncthreads();
  }
}

// ---------------- E1: L0..L4, one block per frame, direct weight loads ----------------
__global__ __launch_bounds__(512, 4)
void encoder1(const float* __restrict__ x, const float* __restrict__ w0,
              const unsigned short* __restrict__ wp123,
              const unsigned short* __restrict__ wp4,
              unsigned short* __restrict__ act4g) {
  __shared__ __align__(16) unsigned short actA[18496];
  __shared__ __align__(16) unsigned short actB[9792];
  float* s_x = (float*)actB;
  const int tid = threadIdx.x;
  const int frame = blockIdx.x;
  const int bb = frame >> 8;
  const int t = (frame & 255) + 256;

  if (tid < 256) s_x[3 + tid] = x[((bb << 8) + tid) * 512 + t];
  else if (tid < 259) s_x[tid - 256] = 0.f;
  else if (tid < 262) s_x[tid] = 0.f;
  wait_lgkm0();
  bar();

  // L0: 1->128, k7 s2 p3 (fp32 VALU), store fp16 parity layout
  {
    const int c = tid & 127;
    const int half = tid >> 7;
    float wv[7];
#pragma unroll
    for (int k = 0; k < 7; ++k) wv[k] = w0[c * 7 + k];
    for (int j = half * 32; j < half * 32 + 32; ++j) {
      float s = 0.f;
#pragma unroll
      for (int k = 0; k < 7; ++k) s += wv[k] * s_x[2 * j + k];
      int row = ((j & 1) ? 68 : 0) + (j >> 1) + 2;
      actA[row * RS + c] = f2h(lrelu(s));
    }
    unsigned int* zp = (unsigned int*)actA;
    for (int s2 = tid; s2 < 2 * 4 * 68; s2 += 512) {
      int col = s2 % 68;
      int rr = s2 / 68;
      int par = rr >> 2, r2 = rr & 3;
      int row = (r2 < 2) ? r2 : (64 + r2);
      zp[((size_t)par * 68 + row) * 68 + col] = 0;
    }
  }
  wait_lgkm0();
  bar();

  mlayer_d<7, 3, 128, 64, 2, 2, 0>(wp123,          actA, actB, nullptr, tid, frame);         // L1
  mlayer_d<7, 3, 64, 32, 1, 2, 0>(wp123 + 114688,  actB, actA, nullptr, tid, frame);         // L2
  mlayer_d<7, 3, 32, 16, 1, 1, 0>(wp123 + 229376,  actA, actA + 5440, nullptr, tid, frame);  // L3
  mlayer_d<3, 1, 16, 8, 1, 1, 1>(wp4,              actA + 5440, nullptr, act4g, tid, frame); // L4 -> global
}

// ---------------- generic MFMA conv layer (encoder2), frag-packed weights ----------------
template<int KW, int POFF, int PIN, int POUT, int FPB, int COUT, int MC, int MN, int OM, bool FLATIN>
__device__ __forceinline__ void mlayer(const unsigned short* __restrict__ wp,
                                       const unsigned short* __restrict__ sin_,
                                       unsigned short* __restrict__ sout,
                                       float* __restrict__ gout,
                                       int tid, int frame0) {
  constexpr int HRIN  = PIN / 2 + 4;
  constexpr int HROUT = POUT / 2 + 4;
  constexpr int NVAL = POUT * FPB;
  constexpr int Nt = (NVAL + 15) / 16;
  constexpr int Ct = COUT / 16;
  constexpr int MCg = Ct / MC, MNg = Nt / MN;
  constexpr int KS = 4;
  constexpr int NS = KW * KS;
  constexpr int DA = NS < 6 ? NS : 6;
  constexpr int DB = NS < 3 ? NS : 3;
  constexpr int L2P = POUT == 1 ? 0 : POUT == 2 ? 1 : POUT == 4 ? 2 : POUT == 8 ? 3 :
                      POUT == 16 ? 4 : POUT == 32 ? 5 : 6;

  const int wid = tid >> 6, lane = tid & 63, nl = lane & 15, q = lane >> 4;

  for (int mac = wid; mac < MCg * MNg; mac += 8) {
    const int mcg = mac / MNg, mng = mac % MNg;
    const int ct0 = mcg * MC, nt0 = mng * MN;
    int jj[MN]; bool val[MN];
#pragma unroll
    for (int jn = 0; jn < MN; ++jn) {
      int n = (nt0 + jn) * 16 + nl;
      val[jn] = (n < NVAL);
      jj[jn] = val[jn] ? n : 0;
    }
    int rofs[MN][KW];
#pragma unroll
    for (int jn = 0; jn < MN; ++jn) {
      const int f = jj[jn] >> L2P, j = jj[jn] & (POUT - 1);
#pragma unroll
      for (int kw = 0; kw < KW; ++kw) {
        if (FLATIN) {
          rofs[jn][kw] = jj[jn] * RS + q * 8;
        } else {
          int P = 2 * j + kw - POFF + 4;
          rofs[jn][kw] = (f * 2 * HRIN + (P & 1) * HRIN + (P >> 1)) * RS + q * 8;
        }
      }
    }
    int abase[MC];
#pragma unroll
    for (int i = 0; i < MC; ++i) abase[i] = (ct0 + i) * 512 + lane * 8;

    f32x4 acc[MC][MN];
#pragma unroll
    for (int i = 0; i < MC; ++i)
#pragma unroll
      for (int jn = 0; jn < MN; ++jn) acc[i][jn] = (f32x4){0.f, 0.f, 0.f, 0.f};

    f16x8 A[DA][MC], B[DB][MN];
#pragma unroll
    for (int s = 0; s < DA; ++s) {
      const int kw = s / KS, ks = s % KS;
#pragma unroll
      for (int i = 0; i < MC; ++i)
        A[s][i] = *(const f16x8*)(wp + (size_t)(kw * KS + ks) * (Ct * 512) + abase[i]);
    }
#pragma unroll
    for (int s = 0; s < DB; ++s) {
      const int kw = s / KS, ks = s % KS;
#pragma unroll
      for (int jn = 0; jn < MN; ++jn)
        B[s][jn] = *(const f16x8*)(sin_ + rofs[jn][kw] + ks * 32);
    }
#pragma unroll
    for (int s = 0; s < NS; ++s) {
      const int sa = s % DA, sb = s % DB;
#pragma unroll
      for (int i = 0; i < MC; ++i)
#pragma unroll
        for (int jn = 0; jn < MN; ++jn)
          acc[i][jn] = __builtin_amdgcn_mfma_f32_16x16x32_f16(A[sa][i], B[sb][jn], acc[i][jn], 0, 0, 0);
      if (s + DA < NS) {
        const int kw = (s + DA) / KS, ks = (s + DA) % KS;
#pragma unroll
        for (int i = 0; i < MC; ++i)
          A[sa][i] = *(const f16x8*)(wp + (size_t)(kw * KS + ks) * (Ct * 512) + abase[i]);
      }
      if (s + DB < NS) {
        const int kw = (s + DB) / KS, ks = (s + DB) % KS;
#pragma unroll
        for (int jn = 0; jn < MN; ++jn)
          B[sb][jn] = *(const f16x8*)(sin_ + rofs[jn][kw] + ks * 32);
      }
    }
#pragma unroll
    for (int i = 0; i < MC; ++i) {
#pragma unroll
      for (int jn = 0; jn < MN; ++jn) {
        if (OM == 3) {
          if (val[jn]) {
            const int frame = frame0 + jj[jn];   // POUT==1
            float4 v = make_float4(acc[i][jn][0], acc[i][jn][1], acc[i][jn][2], acc[i][jn][3]);
            *(float4*)(gout + (size_t)frame * 256 + (ct0 + i) * 16 + q * 4) = v;
          }
        } else if (OM == 2) {
          if (val[jn]) {
            unsigned int lo = (unsigned)f2h(lrelu(acc[i][jn][0])) | ((unsigned)f2h(lrelu(acc[i][jn][1])) << 16);
            unsigned int hi = (unsigned)f2h(lrelu(acc[i][jn][2])) | ((unsigned)f2h(lrelu(acc[i][jn][3])) << 16);
            *(uint2*)(sout + (size_t)jj[jn] * RS + (ct0 + i) * 16 + q * 4) = make_uint2(lo, hi);
          }
        } else {
          if (val[jn]) {
            const int f = jj[jn] >> L2P, j = jj[jn] & (POUT - 1);
            const int row = f * 2 * HROUT + (j & 1) * HROUT + (j >> 1) + 2;
            unsigned int lo = (unsigned)f2h(lrelu(acc[i][jn][0])) | ((unsigned)f2h(lrelu(acc[i][jn][1])) << 16);
            unsigned int hi = (unsigned)f2h(lrelu(acc[i][jn][2])) | ((unsigned)f2h(lrelu(acc[i][jn][3])) << 16);
            *(uint2*)(sout + (size_t)row * RS + (ct0 + i) * 16 + q * 4) = make_uint2(lo, hi);
          }
        }
      }
    }
  }
  if (OM == 0) {
    constexpr int DEND = ((POUT - 1) >> 1) + 3;
    constexpr int NZ = 2 + (HROUT - DEND);
    constexpr int TOTU = FPB * 2 * NZ * (RS / 2);
    unsigned int* zp = (unsigned int*)sout;
    for (int s2 = tid; s2 < TOTU; s2 += 512) {
      int col = s2 % 68;
      int rr = s2 / 68;
      int fr = rr / (2 * NZ), r2 = rr % (2 * NZ);
      int par = r2 / NZ, rz = r2 % NZ;
      int row = rz < 2 ? rz : DEND + rz - 2;
      zp[((size_t)(fr * 2 + par) * HROUT + row) * 68 + col] = 0;
    }
    __syncthreads();
  } else if (OM == 2) {
    __syncthreads();
  }
}

// ---------------- E2: L5..L8, 8 frames per block ----------------
__global__ __launch_bounds__(512)
void encoder2(const unsigned short* __restrict__ act4g,
              const unsigned short* __restrict__ wp4,
              const unsigned short* __restrict__ wp8,
              float* __restrict__ h) {
  __shared__ __align__(16) unsigned short actP[17408];
  __shared__ __align__(16) unsigned short actQ[13056];
  __shared__ __align__(16) unsigned short actR[2176];
  const int tid = threadIdx.x;
  const int frame0 = blockIdx.x * 8;

  {
    uint4 z4 = make_uint4(0, 0, 0, 0);
    for (int s = tid; s < 2176; s += 512) ((uint4*)actP)[s] = z4;
    for (int s = tid; s < 1632; s += 512) ((uint4*)actQ)[s] = z4;
    for (int s = tid; s < 272; s += 512) ((uint4*)actR)[s] = z4;
  }
  __syncthreads();
  for (int c = tid; c < 1024; c += 512) {
    int f = c >> 7, rem = c & 127, pos = rem >> 4, o = (rem & 15) * 8;
    uint4 v = *(const uint4*)(act4g + ((size_t)(frame0 + f) * 8 + pos) * 128 + o);
    int P = pos + 4;
    int row = (P & 1) * 8 + (P >> 1);
    *(uint4*)(actP + ((size_t)f * 16 + row) * RS + o) = v;
  }
  __syncthreads();

  mlayer<3, 1, 8, 4, 8, 128, 2, 1, 0, false>(wp4 + 49152,  actP, actQ, nullptr, tid, frame0);  // L5
  mlayer<3, 1, 4, 2, 8, 128, 1, 1, 0, false>(wp4 + 98304,  actQ, actP, nullptr, tid, frame0);  // L6
  mlayer<3, 1, 2, 1, 8, 128, 1, 1, 2, false>(wp4 + 147456, actP, actR, nullptr, tid, frame0);  // L7 flat
  mlayer<1, 0, 1, 1, 8, 256, 1, 1, 3, true>(wp8,           actR, nullptr, h, tid, frame0);     // L8 -> h fp32
}

// ---------------- Fused WaveNet: all 8 layers + finalize, cooperative launch ----------------
// Grid fixed at 256 blocks x 256 threads; grid-wide sync via cg::this_grid().
__global__ __launch_bounds__(256)
void wnet_all(const unsigned short* __restrict__ wn,
              float* __restrict__ h0, float* __restrict__ h1,
              float* __restrict__ feats, const float* __restrict__ jw,
              float* __restrict__ out) {
  cg::grid_group grid = cg::this_grid();
  const int tid = threadIdx.x;
  const int blk = blockIdx.x;
  const int wid = tid >> 6, lane = tid & 63, nl = lane & 15, q = lane >> 4;
  __shared__ __align__(16) unsigned short sB[16 * 520];
  float* hs = h0; float* hd = h1;

  for (int li = 0; li < 8; ++li) {
    const int npos = 128 >> li, p = 1 << li, N = npos * 8, lnp = 7 - li;
    const int nN = (N + 15) >> 4;
    const unsigned short* wl = wn + (size_t)li * 262144;

    if (blk < 4 * nN) {
      const int nb = blk >> 2, mb = blk & 3;
      const int n0 = nb * 16;
      // stage B: 16 positions x 512 k (fp32 -> fp16), k<256 -> t-p row, k>=256 -> t row
      for (int c = tid; c < 1024; c += 256) {
        const int nr = c >> 6, o = (c & 63) * 8;
        const int n = n0 + nr;
        unsigned short tmp[8] = {0, 0, 0, 0, 0, 0, 0, 0};
        if (n < N) {
          const int b = n >> lnp, kk = n & (npos - 1);
          const int t = 255 - (kk << (li + 1));
          const float* src = (o < 256) ? hs + ((size_t)(b * 256 + t - p)) * 256 + o
                                       : hs + ((size_t)(b * 256 + t)) * 256 + (o - 256);
#pragma unroll
          for (int e = 0; e < 8; ++e) tmp[e] = f2h(src[e]);
        }
        unsigned int u0 = (unsigned)tmp[0] | ((unsigned)tmp[1] << 16);
        unsigned int u1 = (unsigned)tmp[2] | ((unsigned)tmp[3] << 16);
        unsigned int u2 = (unsigned)tmp[4] | ((unsigned)tmp[5] << 16);
        unsigned int u3 = (unsigned)tmp[6] | ((unsigned)tmp[7] << 16);
        *(uint4*)(sB + (size_t)nr * 520 + o) = make_uint4(u0, u1, u2, u3);
      }
      __syncthreads();

      f32x4 acc[2];
      acc[0] = (f32x4){0.f, 0.f, 0.f, 0.f};
      acc[1] = (f32x4){0.f, 0.f, 0.f, 0.f};
      int arow[2];
#pragma unroll
      for (int i = 0; i < 2; ++i) arow[i] = (mb * 8 + wid * 2 + i) * 512 + lane * 8;
      const int bofs = nl * 520 + q * 8;

      f16x8 A[4][2], Bv[2];
#pragma unroll
      for (int s = 0; s < 4; ++s)
#pragma unroll
        for (int i = 0; i < 2; ++i) A[s][i] = *(const f16x8*)(wl + arow[i] + (size_t)s * 16384);
#pragma unroll
      for (int s = 0; s < 2; ++s) Bv[s] = *(const f16x8*)(sB + bofs + s * 32);
#pragma unroll
      for (int s = 0; s < 16; ++s) {
        const int sa = s & 3, sb = s & 1;
        acc[0] = __builtin_amdgcn_mfma_f32_16x16x32_f16(A[sa][0], Bv[sb], acc[0], 0, 0, 0);
        acc[1] = __builtin_amdgcn_mfma_f32_16x16x32_f16(A[sa][1], Bv[sb], acc[1], 0, 0, 0);
        if (s + 4 < 16) {
#pragma unroll
          for (int i = 0; i < 2; ++i) A[sa][i] = *(const f16x8*)(wl + arow[i] + (size_t)(s + 4) * 16384);
        }
        if (s + 2 < 16) Bv[sb] = *(const f16x8*)(sB + bofs + (s + 2) * 32);
      }

      const int n = n0 + nl;
      if (n < N) {
        const int b = n >> lnp, kk = n & (npos - 1);
        const int t = 255 - (kk << (li + 1));
        const size_t rowoff = ((size_t)(b * 256 + t)) * 256;
#pragma unroll
        for (int i = 0; i < 2; ++i) {
          const int ch = mb * 64 + (wid * 2 + i) * 8 + q * 2;
          const float z0 = tanhf(acc[i][0]) * (1.f / (1.f + expf(-acc[i][1])));
          const float z1 = tanhf(acc[i][2]) * (1.f / (1.f + expf(-acc[i][3])));
          float2 hv = *(const float2*)(hs + rowoff + ch);
          *(float2*)(hd + rowoff + ch) = make_float2(hv.x + z0, hv.y + z1);
          if (kk == 0) {
            float* fp = feats + b * 256 + ch;
            if (li == 0) { fp[0] = z0; fp[1] = z1; }
            else         { fp[0] += z0; fp[1] += z1; }
          }
        }
      }
      __syncthreads();   // sB reuse safety before next layer's stage
    }
    __threadfence();
    grid.sync();
    float* tsw = hs; hs = hd; hd = tsw;
  }

  // finalize: feats complete and visible after the 8th grid sync
  if (blk < NB) {
    float* red = (float*)sB;
    const float v = feats[blk * 256 + tid];
    out[blk * 256 + tid] = v;
    red[tid] = v * jw[tid];
    __syncthreads();
    for (int s = 128; s > 0; s >>= 1) {
      if (tid < s) red[tid] += red[tid + s];
      __syncthreads();
    }
    if (tid == 0) out[NB * 256 + blk] = red[0];
  }
}

extern "C" void kernel_launch(void* const* d_in, const int* in_sizes, int n_in,
                              void* d_out, int out_size, void* d_ws, size_t ws_size,
                              hipStream_t stream) {
  const float* x     = (const float*)d_in[0];
  const float* w0    = (const float*)d_in[1];
  const float* w123  = (const float*)d_in[2];
  const float* w4567 = (const float*)d_in[3];
  const float* w8    = (const float*)d_in[4];
  const float* mw    = (const float*)d_in[5];
  const float* gw    = (const float*)d_in[6];
  const float* jw    = (const float*)d_in[7];
  float* out = (float*)d_out;

  float* ws = (float*)d_ws;
  unsigned short* act4g = (unsigned short*)ws;            // 2,097,152 fp16
  float* h0    = ws + 1048576;                            // 524,288 f
  float* h1    = ws + 1572864;                            // 524,288 f
  float* feats = ws + 2097152;                            // 2,048 f
  unsigned short* wp = (unsigned short*)(ws + 2099200);   // 573,440 fp16
  unsigned short* wn = (unsigned short*)(ws + 2385920);   // 2,097,152 fp16

  pack_kernel<<<5216, 512, 0, stream>>>(w123, w4567, w8, mw, gw, wp, wn);
  encoder1<<<2048, 512, 0, stream>>>(x, w0, wp, wp + N1, act4g);
  encoder2<<<256, 512, 0, stream>>>(act4g, wp + N1, wp + N1 + N2, h0);

  const unsigned short* wnc = wn;
  const float* jwc = jw;
  void* kargs[] = {(void*)&wnc, (void*)&h0, (void*)&h1,
                   (void*)&feats, (void*)&jwc, (void*)&out};
  hipLaunchCooperativeKernel((void*)wnet_all, dim3(256), dim3(256), kargs, 0, stream);
}

// Round 4
// 218.272 us; speedup vs baseline: 2.8387x; 2.8387x over previous
//
#include <hip/hip_runtime.h>
#include <math.h>

#define FC 256
#define NB 8
#define RS 136   // LDS act row stride in fp16 elems (128 ci + 8 pad)

typedef __attribute__((ext_vector_type(8))) _Float16 f16x8;
typedef __attribute__((ext_vector_type(4))) float f32x4;

__device__ __forceinline__ float lrelu(float v) { return fmaxf(v, 0.2f * v); }
__device__ __forceinline__ unsigned short f2h(float f) {
  _Float16 h = (_Float16)f;
  return *(unsigned short*)&h;
}
__device__ __forceinline__ void bar() { asm volatile("s_barrier" ::: "memory"); }
__device__ __forceinline__ void wait_lgkm0() { asm volatile("s_waitcnt lgkmcnt(0)" ::: "memory"); }

// ---------------- weight pack: fp32 -> fp16, MFMA A-fragment layout ----------------
// Encoder layers: per (l,kw,ks,ct): 64 lanes x 8 halves; co = ct*16 + (lane&15),
// ci = ks*32 + (lane>>4)*8 + e. A-load for a wave = one contiguous 1KB burst.
#define N1 344064   // 3*7*128*128   enc w123
#define N2 196608   // 4*3*128*128   enc w4567
#define N3 32768    // 256*128       enc w8 (Ct=16)
#define NTOT 573440
#define NWN 2097152 // 8*512*512     wnet: per (li,k32,rt): row=rt*16+(lane&15), k=k32*32+(lane>>4)*8+e

__global__ void pack_kernel(const float* __restrict__ w123,
                            const float* __restrict__ w4567,
                            const float* __restrict__ w8,
                            const float* __restrict__ mw,
                            const float* __restrict__ gw,
                            unsigned short* __restrict__ wp,
                            unsigned short* __restrict__ wn) {
  int idx = blockIdx.x * 512 + threadIdx.x;
  if (idx < N1) {
    int e = idx & 7, lane = (idx >> 3) & 63, ct = (idx >> 9) & 7, ks = (idx >> 12) & 3, t = idx >> 14;
    int l = t / 7, kw = t % 7;
    int co = ct * 16 + (lane & 15), ci = ks * 32 + (lane >> 4) * 8 + e;
    wp[idx] = f2h(w123[(((l * 128 + co) * 128) + ci) * 7 + kw]);
  } else if (idx < N1 + N2) {
    int k = idx - N1;
    int e = k & 7, lane = (k >> 3) & 63, ct = (k >> 9) & 7, ks = (k >> 12) & 3, t = k >> 14;
    int l = t / 3, kw = t % 3;
    int co = ct * 16 + (lane & 15), ci = ks * 32 + (lane >> 4) * 8 + e;
    wp[idx] = f2h(w4567[(((l * 128 + co) * 128) + ci) * 3 + kw]);
  } else if (idx < NTOT) {
    int k = idx - N1 - N2;
    int e = k & 7, lane = (k >> 3) & 63, ct = (k >> 9) & 15, ks = (k >> 13) & 3;
    int co = ct * 16 + (lane & 15), ci = ks * 32 + (lane >> 4) * 8 + e;
    wp[idx] = f2h(w8[co * 128 + ci]);
  } else if (idx < NTOT + NWN) {
    int k2 = idx - NTOT;
    int li = k2 >> 18, w = k2 & 262143;
    int e = w & 7, lane = (w >> 3) & 63, rt = (w >> 9) & 31, k32 = w >> 14;
    int row = rt * 16 + (lane & 15), k = k32 * 32 + (lane >> 4) * 8 + e;
    int ch = row >> 1, mat = row & 1, kw = k >> 8, ci = k & 255;
    const float* src = mat ? gw : mw;
    wn[k2] = f2h(src[(((size_t)li * 256 + ch) * 256 + ci) * 2 + kw]);
  }
}

// ---------------- direct-load MFMA conv layer (encoder1): no staging, no intra-layer barriers ----
template<int KW, int POFF, int PIN, int POUT, int MC, int MN, int OM>
__device__ __forceinline__ void mlayer_d(const unsigned short* __restrict__ wp,
                                         const unsigned short* __restrict__ sin_,
                                         unsigned short* __restrict__ sout,
                                         unsigned short* __restrict__ gact,
                                         int tid, int frame) {
  constexpr int HRIN = PIN / 2 + 4;
  constexpr int HROUT = POUT / 2 + 4;
  constexpr int Nt = (POUT + 15) / 16;
  constexpr int MNg = Nt / MN;
  constexpr int MCg = 8 / MNg;
  static_assert(MC * MCg == 8, "cout tiling must cover 128 channels");
  constexpr int NS = KW * 4;
  constexpr int DA = NS < 6 ? NS : 6;                      // deeper A prefetch (L2 latency)
  constexpr int DB = MC == 1 ? (NS < 4 ? NS : 4) : (NS < 3 ? NS : 3);

  const int wid = tid >> 6, lane = tid & 63, nl = lane & 15, q = lane >> 4;
  const int mcg = wid / MNg, mng = wid % MNg;
  const int ct0 = mcg * MC, nt0 = mng * MN;

  int jj[MN]; bool val[MN]; int rofs[MN][KW];
#pragma unroll
  for (int jn = 0; jn < MN; ++jn) {
    int n = (nt0 + jn) * 16 + nl;
    val[jn] = (n < POUT);
    jj[jn] = val[jn] ? n : 0;
#pragma unroll
    for (int kw = 0; kw < KW; ++kw) {
      int P = 2 * jj[jn] + kw - POFF + 4;
      rofs[jn][kw] = ((P & 1) * HRIN + (P >> 1)) * RS + q * 8;
    }
  }
  const unsigned short* wl = wp + (size_t)ct0 * 512 + lane * 8;

  f32x4 acc[MC][MN];
#pragma unroll
  for (int i = 0; i < MC; ++i)
#pragma unroll
    for (int jn = 0; jn < MN; ++jn) acc[i][jn] = (f32x4){0.f, 0.f, 0.f, 0.f};

  f16x8 A[DA][MC], B[DB][MN];
#pragma unroll
  for (int s = 0; s < DA; ++s)
#pragma unroll
    for (int i = 0; i < MC; ++i)
      A[s][i] = *(const f16x8*)(wl + (size_t)s * 4096 + i * 512);
#pragma unroll
  for (int s = 0; s < DB; ++s) {
    const int kw = s >> 2, ks = s & 3;
#pragma unroll
    for (int jn = 0; jn < MN; ++jn)
      B[s][jn] = *(const f16x8*)(sin_ + rofs[jn][kw] + ks * 32);
  }
#pragma unroll
  for (int s = 0; s < NS; ++s) {
    const int sa = s % DA, sb = s % DB;
#pragma unroll
    for (int i = 0; i < MC; ++i)
#pragma unroll
      for (int jn = 0; jn < MN; ++jn)
        acc[i][jn] = __builtin_amdgcn_mfma_f32_16x16x32_f16(A[sa][i], B[sb][jn], acc[i][jn], 0, 0, 0);
    if (s + DA < NS) {
#pragma unroll
      for (int i = 0; i < MC; ++i)
        A[sa][i] = *(const f16x8*)(wl + (size_t)(s + DA) * 4096 + i * 512);
    }
    if (s + DB < NS) {
      const int kw = (s + DB) >> 2, ks = (s + DB) & 3;
#pragma unroll
      for (int jn = 0; jn < MN; ++jn)
        B[sb][jn] = *(const f16x8*)(sin_ + rofs[jn][kw] + ks * 32);
    }
  }

#pragma unroll
  for (int i = 0; i < MC; ++i) {
#pragma unroll
    for (int jn = 0; jn < MN; ++jn) {
      if (!val[jn]) continue;
      unsigned int lo = (unsigned)f2h(lrelu(acc[i][jn][0])) | ((unsigned)f2h(lrelu(acc[i][jn][1])) << 16);
      unsigned int hi = (unsigned)f2h(lrelu(acc[i][jn][2])) | ((unsigned)f2h(lrelu(acc[i][jn][3])) << 16);
      const int j = jj[jn];
      if (OM == 1) {
        *(uint2*)(gact + ((size_t)frame * POUT + j) * 128 + (ct0 + i) * 16 + q * 4) = make_uint2(lo, hi);
      } else {
        const int row = (j & 1) * HROUT + (j >> 1) + 2;
        *(uint2*)(sout + (size_t)row * RS + (ct0 + i) * 16 + q * 4) = make_uint2(lo, hi);
      }
    }
  }
  if (OM == 0) {
    constexpr int DEND = ((POUT - 1) >> 1) + 3;
    constexpr int NZ = 2 + (HROUT - DEND);
    unsigned int* zp = (unsigned int*)sout;
    for (int s2 = tid; s2 < 2 * NZ * 68; s2 += 512) {
      int col = s2 % 68, rr = s2 / 68;
      int par = rr / NZ, rz = rr % NZ;
      int row = rz < 2 ? rz : DEND + rz - 2;
      zp[((size_t)par * HROUT + row) * 68 + col] = 0;
    }
    __syncthreads();
  }
}

// ---------------- E1: L0..L4, one block per frame, direct weight loads ----------------
__global__ __launch_bounds__(512, 4)
void encoder1(const float* __restrict__ x, const float* __restrict__ w0,
              const unsigned short* __restrict__ wp123,
              const unsigned short* __restrict__ wp4,
              unsigned short* __restrict__ act4g) {
  __shared__ __align__(16) unsigned short actA[18496];
  __shared__ __align__(16) unsigned short actB[9792];
  float* s_x = (float*)actB;
  const int tid = threadIdx.x;
  const int frame = blockIdx.x;
  const int bb = frame >> 8;
  const int t = (frame & 255) + 256;

  if (tid < 256) s_x[3 + tid] = x[((bb << 8) + tid) * 512 + t];
  else if (tid < 259) s_x[tid - 256] = 0.f;
  else if (tid < 262) s_x[tid] = 0.f;
  wait_lgkm0();
  bar();

  // L0: 1->128, k7 s2 p3 (fp32 VALU), store fp16 parity layout
  {
    const int c = tid & 127;
    const int half = tid >> 7;
    float wv[7];
#pragma unroll
    for (int k = 0; k < 7; ++k) wv[k] = w0[c * 7 + k];
    for (int j = half * 32; j < half * 32 + 32; ++j) {
      float s = 0.f;
#pragma unroll
      for (int k = 0; k < 7; ++k) s += wv[k] * s_x[2 * j + k];
      int row = ((j & 1) ? 68 : 0) + (j >> 1) + 2;
      actA[row * RS + c] = f2h(lrelu(s));
    }
    unsigned int* zp = (unsigned int*)actA;
    for (int s2 = tid; s2 < 2 * 4 * 68; s2 += 512) {
      int col = s2 % 68;
      int rr = s2 / 68;
      int par = rr >> 2, r2 = rr & 3;
      int row = (r2 < 2) ? r2 : (64 + r2);
      zp[((size_t)par * 68 + row) * 68 + col] = 0;
    }
  }
  wait_lgkm0();
  bar();

  mlayer_d<7, 3, 128, 64, 2, 2, 0>(wp123,          actA, actB, nullptr, tid, frame);         // L1
  mlayer_d<7, 3, 64, 32, 1, 2, 0>(wp123 + 114688,  actB, actA, nullptr, tid, frame);         // L2
  mlayer_d<7, 3, 32, 16, 1, 1, 0>(wp123 + 229376,  actA, actA + 5440, nullptr, tid, frame);  // L3
  mlayer_d<3, 1, 16, 8, 1, 1, 1>(wp4,              actA + 5440, nullptr, act4g, tid, frame); // L4 -> global
}

// ---------------- generic MFMA conv layer (encoder2), frag-packed weights ----------------
template<int KW, int POFF, int PIN, int POUT, int FPB, int COUT, int MC, int MN, int OM, bool FLATIN>
__device__ __forceinline__ void mlayer(const unsigned short* __restrict__ wp,
                                       const unsigned short* __restrict__ sin_,
                                       unsigned short* __restrict__ sout,
                                       float* __restrict__ gout,
                                       int tid, int frame0) {
  constexpr int HRIN  = PIN / 2 + 4;
  constexpr int HROUT = POUT / 2 + 4;
  constexpr int NVAL = POUT * FPB;
  constexpr int Nt = (NVAL + 15) / 16;
  constexpr int Ct = COUT / 16;
  constexpr int MCg = Ct / MC, MNg = Nt / MN;
  constexpr int KS = 4;
  constexpr int NS = KW * KS;
  constexpr int DA = NS < 6 ? NS : 6;
  constexpr int DB = NS < 3 ? NS : 3;
  constexpr int L2P = POUT == 1 ? 0 : POUT == 2 ? 1 : POUT == 4 ? 2 : POUT == 8 ? 3 :
                      POUT == 16 ? 4 : POUT == 32 ? 5 : 6;

  const int wid = tid >> 6, lane = tid & 63, nl = lane & 15, q = lane >> 4;

  for (int mac = wid; mac < MCg * MNg; mac += 8) {
    const int mcg = mac / MNg, mng = mac % MNg;
    const int ct0 = mcg * MC, nt0 = mng * MN;
    int jj[MN]; bool val[MN];
#pragma unroll
    for (int jn = 0; jn < MN; ++jn) {
      int n = (nt0 + jn) * 16 + nl;
      val[jn] = (n < NVAL);
      jj[jn] = val[jn] ? n : 0;
    }
    int rofs[MN][KW];
#pragma unroll
    for (int jn = 0; jn < MN; ++jn) {
      const int f = jj[jn] >> L2P, j = jj[jn] & (POUT - 1);
#pragma unroll
      for (int kw = 0; kw < KW; ++kw) {
        if (FLATIN) {
          rofs[jn][kw] = jj[jn] * RS + q * 8;
        } else {
          int P = 2 * j + kw - POFF + 4;
          rofs[jn][kw] = (f * 2 * HRIN + (P & 1) * HRIN + (P >> 1)) * RS + q * 8;
        }
      }
    }
    int abase[MC];
#pragma unroll
    for (int i = 0; i < MC; ++i) abase[i] = (ct0 + i) * 512 + lane * 8;

    f32x4 acc[MC][MN];
#pragma unroll
    for (int i = 0; i < MC; ++i)
#pragma unroll
      for (int jn = 0; jn < MN; ++jn) acc[i][jn] = (f32x4){0.f, 0.f, 0.f, 0.f};

    f16x8 A[DA][MC], B[DB][MN];
#pragma unroll
    for (int s = 0; s < DA; ++s) {
      const int kw = s / KS, ks = s % KS;
#pragma unroll
      for (int i = 0; i < MC; ++i)
        A[s][i] = *(const f16x8*)(wp + (size_t)(kw * KS + ks) * (Ct * 512) + abase[i]);
    }
#pragma unroll
    for (int s = 0; s < DB; ++s) {
      const int kw = s / KS, ks = s % KS;
#pragma unroll
      for (int jn = 0; jn < MN; ++jn)
        B[s][jn] = *(const f16x8*)(sin_ + rofs[jn][kw] + ks * 32);
    }
#pragma unroll
    for (int s = 0; s < NS; ++s) {
      const int sa = s % DA, sb = s % DB;
#pragma unroll
      for (int i = 0; i < MC; ++i)
#pragma unroll
        for (int jn = 0; jn < MN; ++jn)
          acc[i][jn] = __builtin_amdgcn_mfma_f32_16x16x32_f16(A[sa][i], B[sb][jn], acc[i][jn], 0, 0, 0);
      if (s + DA < NS) {
        const int kw = (s + DA) / KS, ks = (s + DA) % KS;
#pragma unroll
        for (int i = 0; i < MC; ++i)
          A[sa][i] = *(const f16x8*)(wp + (size_t)(kw * KS + ks) * (Ct * 512) + abase[i]);
      }
      if (s + DB < NS) {
        const int kw = (s + DB) / KS, ks = (s + DB) % KS;
#pragma unroll
        for (int jn = 0; jn < MN; ++jn)
          B[sb][jn] = *(const f16x8*)(sin_ + rofs[jn][kw] + ks * 32);
      }
    }
#pragma unroll
    for (int i = 0; i < MC; ++i) {
#pragma unroll
      for (int jn = 0; jn < MN; ++jn) {
        if (OM == 3) {
          if (val[jn]) {
            const int frame = frame0 + jj[jn];   // POUT==1
            float4 v = make_float4(acc[i][jn][0], acc[i][jn][1], acc[i][jn][2], acc[i][jn][3]);
            *(float4*)(gout + (size_t)frame * 256 + (ct0 + i) * 16 + q * 4) = v;
          }
        } else if (OM == 2) {
          if (val[jn]) {
            unsigned int lo = (unsigned)f2h(lrelu(acc[i][jn][0])) | ((unsigned)f2h(lrelu(acc[i][jn][1])) << 16);
            unsigned int hi = (unsigned)f2h(lrelu(acc[i][jn][2])) | ((unsigned)f2h(lrelu(acc[i][jn][3])) << 16);
            *(uint2*)(sout + (size_t)jj[jn] * RS + (ct0 + i) * 16 + q * 4) = make_uint2(lo, hi);
          }
        } else {
          if (val[jn]) {
            const int f = jj[jn] >> L2P, j = jj[jn] & (POUT - 1);
            const int row = f * 2 * HROUT + (j & 1) * HROUT + (j >> 1) + 2;
            unsigned int lo = (unsigned)f2h(lrelu(acc[i][jn][0])) | ((unsigned)f2h(lrelu(acc[i][jn][1])) << 16);
            unsigned int hi = (unsigned)f2h(lrelu(acc[i][jn][2])) | ((unsigned)f2h(lrelu(acc[i][jn][3])) << 16);
            *(uint2*)(sout + (size_t)row * RS + (ct0 + i) * 16 + q * 4) = make_uint2(lo, hi);
          }
        }
      }
    }
  }
  if (OM == 0) {
    constexpr int DEND = ((POUT - 1) >> 1) + 3;
    constexpr int NZ = 2 + (HROUT - DEND);
    constexpr int TOTU = FPB * 2 * NZ * (RS / 2);
    unsigned int* zp = (unsigned int*)sout;
    for (int s2 = tid; s2 < TOTU; s2 += 512) {
      int col = s2 % 68;
      int rr = s2 / 68;
      int fr = rr / (2 * NZ), r2 = rr % (2 * NZ);
      int par = r2 / NZ, rz = r2 % NZ;
      int row = rz < 2 ? rz : DEND + rz - 2;
      zp[((size_t)(fr * 2 + par) * HROUT + row) * 68 + col] = 0;
    }
    __syncthreads();
  } else if (OM == 2) {
    __syncthreads();
  }
}

// ---------------- E2: L5..L8, 8 frames per block ----------------
__global__ __launch_bounds__(512)
void encoder2(const unsigned short* __restrict__ act4g,
              const unsigned short* __restrict__ wp4,
              const unsigned short* __restrict__ wp8,
              float* __restrict__ h) {
  __shared__ __align__(16) unsigned short actP[17408];
  __shared__ __align__(16) unsigned short actQ[13056];
  __shared__ __align__(16) unsigned short actR[2176];
  const int tid = threadIdx.x;
  const int frame0 = blockIdx.x * 8;

  {
    uint4 z4 = make_uint4(0, 0, 0, 0);
    for (int s = tid; s < 2176; s += 512) ((uint4*)actP)[s] = z4;
    for (int s = tid; s < 1632; s += 512) ((uint4*)actQ)[s] = z4;
    for (int s = tid; s < 272; s += 512) ((uint4*)actR)[s] = z4;
  }
  __syncthreads();
  for (int c = tid; c < 1024; c += 512) {
    int f = c >> 7, rem = c & 127, pos = rem >> 4, o = (rem & 15) * 8;
    uint4 v = *(const uint4*)(act4g + ((size_t)(frame0 + f) * 8 + pos) * 128 + o);
    int P = pos + 4;
    int row = (P & 1) * 8 + (P >> 1);
    *(uint4*)(actP + ((size_t)f * 16 + row) * RS + o) = v;
  }
  __syncthreads();

  mlayer<3, 1, 8, 4, 8, 128, 2, 1, 0, false>(wp4 + 49152,  actP, actQ, nullptr, tid, frame0);  // L5
  mlayer<3, 1, 4, 2, 8, 128, 1, 1, 0, false>(wp4 + 98304,  actQ, actP, nullptr, tid, frame0);  // L6
  mlayer<3, 1, 2, 1, 8, 128, 1, 1, 2, false>(wp4 + 147456, actP, actR, nullptr, tid, frame0);  // L7 flat
  mlayer<1, 0, 1, 1, 8, 256, 1, 1, 3, true>(wp8,           actR, nullptr, h, tid, frame0);     // L8 -> h fp32
}

// ---------------- WaveNet fused layer, all li; finalize fused at li==7 ----------------
__global__ __launch_bounds__(256)
void wnet_kernel(const unsigned short* __restrict__ wn,
                 const float* __restrict__ hsrc, float* __restrict__ hdst,
                 float* __restrict__ feats, const float* __restrict__ jw,
                 float* __restrict__ out, int li) {
  const int npos = 128 >> li, p = 1 << li, N = npos * 8, lnp = 7 - li;
  const int tid = threadIdx.x;
  const int nb = blockIdx.x >> 2, mb = blockIdx.x & 3;
  const int n0 = nb * 16;
  __shared__ __align__(16) unsigned short sB[16 * 520];
  __shared__ float jls[8];

  for (int c = tid; c < 1024; c += 256) {
    const int nr = c >> 6, o = (c & 63) * 8;
    const int n = n0 + nr;
    unsigned short tmp[8] = {0, 0, 0, 0, 0, 0, 0, 0};
    if (n < N) {
      const int b = n >> lnp, kk = n & (npos - 1);
      const int t = 255 - (kk << (li + 1));
      const float* src = (o < 256) ? hsrc + ((size_t)(b * 256 + t - p)) * 256 + o
                                   : hsrc + ((size_t)(b * 256 + t)) * 256 + (o - 256);
#pragma unroll
      for (int e = 0; e < 8; ++e) tmp[e] = f2h(src[e]);
    }
    unsigned int u0 = (unsigned)tmp[0] | ((unsigned)tmp[1] << 16);
    unsigned int u1 = (unsigned)tmp[2] | ((unsigned)tmp[3] << 16);
    unsigned int u2 = (unsigned)tmp[4] | ((unsigned)tmp[5] << 16);
    unsigned int u3 = (unsigned)tmp[6] | ((unsigned)tmp[7] << 16);
    *(uint4*)(sB + (size_t)nr * 520 + o) = make_uint4(u0, u1, u2, u3);
  }
  __syncthreads();

  const int wid = tid >> 6, lane = tid & 63, nl = lane & 15, q = lane >> 4;
  f32x4 acc[2];
  acc[0] = (f32x4){0.f, 0.f, 0.f, 0.f};
  acc[1] = (f32x4){0.f, 0.f, 0.f, 0.f};
  int arow[2];
#pragma unroll
  for (int i = 0; i < 2; ++i) arow[i] = (mb * 8 + wid * 2 + i) * 512 + lane * 8;
  const int bofs = nl * 520 + q * 8;

  f16x8 A[4][2], Bv[2];
#pragma unroll
  for (int s = 0; s < 4; ++s)
#pragma unroll
    for (int i = 0; i < 2; ++i) A[s][i] = *(const f16x8*)(wn + arow[i] + (size_t)s * 16384);
#pragma unroll
  for (int s = 0; s < 2; ++s) Bv[s] = *(const f16x8*)(sB + bofs + s * 32);
#pragma unroll
  for (int s = 0; s < 16; ++s) {
    const int sa = s & 3, sb = s & 1;
    acc[0] = __builtin_amdgcn_mfma_f32_16x16x32_f16(A[sa][0], Bv[sb], acc[0], 0, 0, 0);
    acc[1] = __builtin_amdgcn_mfma_f32_16x16x32_f16(A[sa][1], Bv[sb], acc[1], 0, 0, 0);
    if (s + 4 < 16) {
#pragma unroll
      for (int i = 0; i < 2; ++i) A[sa][i] = *(const f16x8*)(wn + arow[i] + (size_t)(s + 4) * 16384);
    }
    if (s + 2 < 16) Bv[sb] = *(const f16x8*)(sB + bofs + (s + 2) * 32);
  }

  const int n = n0 + nl;
  if (li < 7) {
    if (n < N) {
      const int b = n >> lnp, kk = n & (npos - 1);
      const int t = 255 - (kk << (li + 1));
      const size_t rowoff = ((size_t)(b * 256 + t)) * 256;
#pragma unroll
      for (int i = 0; i < 2; ++i) {
        const int ch = mb * 64 + (wid * 2 + i) * 8 + q * 2;
        const float z0 = tanhf(acc[i][0]) * (1.f / (1.f + expf(-acc[i][1])));
        const float z1 = tanhf(acc[i][2]) * (1.f / (1.f + expf(-acc[i][3])));
        float2 hv = *(const float2*)(hsrc + rowoff + ch);
        *(float2*)(hdst + rowoff + ch) = make_float2(hv.x + z0, hv.y + z1);
        if (kk == 0) {
          float* fp = feats + b * 256 + ch;
          if (li == 0) { fp[0] = z0; fp[1] = z1; }
          else         { fp[0] += z0; fp[1] += z1; }
        }
      }
    }
  } else {
    // li == 7: final layer + fused finalize. 4 blocks (mb), each covers all 8
    // batches (n = nl < 8) and 64 output channels. j partials via LDS + global atomics.
    if (tid < 8) jls[tid] = 0.f;
    __syncthreads();
    if (n < N) {
      const int b = n;                    // lnp == 0, kk == 0, t == 255
      float partial = 0.f;
#pragma unroll
      for (int i = 0; i < 2; ++i) {
        const int ch = mb * 64 + (wid * 2 + i) * 8 + q * 2;
        const float z0 = tanhf(acc[i][0]) * (1.f / (1.f + expf(-acc[i][1])));
        const float z1 = tanhf(acc[i][2]) * (1.f / (1.f + expf(-acc[i][3])));
        const float* fp = feats + b * 256 + ch;
        const float f0 = fp[0] + z0;
        const float f1 = fp[1] + z1;
        *(float2*)(out + b * 256 + ch) = make_float2(f0, f1);
        partial += f0 * jw[ch] + f1 * jw[ch + 1];
      }
      atomicAdd(&jls[b], partial);
    }
    __syncthreads();
    if (tid < 8) atomicAdd(out + NB * 256 + tid, jls[tid]);
  }
}

extern "C" void kernel_launch(void* const* d_in, const int* in_sizes, int n_in,
                              void* d_out, int out_size, void* d_ws, size_t ws_size,
                              hipStream_t stream) {
  const float* x     = (const float*)d_in[0];
  const float* w0    = (const float*)d_in[1];
  const float* w123  = (const float*)d_in[2];
  const float* w4567 = (const float*)d_in[3];
  const float* w8    = (const float*)d_in[4];
  const float* mw    = (const float*)d_in[5];
  const float* gw    = (const float*)d_in[6];
  const float* jw    = (const float*)d_in[7];
  float* out = (float*)d_out;

  float* ws = (float*)d_ws;
  unsigned short* act4g = (unsigned short*)ws;            // 2,097,152 fp16
  float* h0    = ws + 1048576;                            // 524,288 f
  float* h1    = ws + 1572864;                            // 524,288 f
  float* feats = ws + 2097152;                            // 2,048 f
  unsigned short* wp = (unsigned short*)(ws + 2099200);   // 573,440 fp16
  unsigned short* wn = (unsigned short*)(ws + 2385920);   // 2,097,152 fp16

  hipMemsetAsync(out + NB * 256, 0, NB * sizeof(float), stream);  // j accumulator slots
  pack_kernel<<<5216, 512, 0, stream>>>(w123, w4567, w8, mw, gw, wp, wn);
  encoder1<<<2048, 512, 0, stream>>>(x, w0, wp, wp + N1, act4g);
  encoder2<<<256, 512, 0, stream>>>(act4g, wp + N1, wp + N1 + N2, h0);

  float* hs = h0; float* hd = h1;
  for (int i = 0; i < 8; ++i) {
    const unsigned short* wl = wn + (size_t)i * 262144;
    const int N = (128 >> i) * 8;
    const int nN = (N + 15) / 16;
    wnet_kernel<<<4 * nN, 256, 0, stream>>>(wl, hs, hd, feats, jw, out, i);
    float* tmp = hd; hd = hs; hs = tmp;
  }
}

// Round 5
// 212.673 us; speedup vs baseline: 2.9135x; 1.0263x over previous
//
#include <hip/hip_runtime.h>
#include <math.h>

#define FC 256
#define NB 8
#define RS 136   // LDS act row stride in fp16 elems (128 ci + 8 pad)

typedef __attribute__((ext_vector_type(8))) _Float16 f16x8;
typedef __attribute__((ext_vector_type(4))) float f32x4;

__device__ __forceinline__ float lrelu(float v) { return fmaxf(v, 0.2f * v); }
__device__ __forceinline__ unsigned short f2h(float f) {
  _Float16 h = (_Float16)f;
  return *(unsigned short*)&h;
}
__device__ __forceinline__ void bar() { asm volatile("s_barrier" ::: "memory"); }
__device__ __forceinline__ void wait_lgkm0() { asm volatile("s_waitcnt lgkmcnt(0)" ::: "memory"); }

// ---------------- weight pack: fp32 -> fp16, MFMA A-fragment layout ----------------
// Encoder layers: per (l,kw,ks,ct): 64 lanes x 8 halves; co = ct*16 + (lane&15),
// ci = ks*32 + (lane>>4)*8 + e. A-load for a wave = one contiguous 1KB burst.
#define N1 344064   // 3*7*128*128   enc w123
#define N2 196608   // 4*3*128*128   enc w4567
#define N3 32768    // 256*128       enc w8 (Ct=16)
#define NTOT 573440
#define NWN 2097152 // 8*512*512     wnet: per (li,k32,rt): row=rt*16+(lane&15), k=k32*32+(lane>>4)*8+e

__global__ void pack_kernel(const float* __restrict__ w123,
                            const float* __restrict__ w4567,
                            const float* __restrict__ w8,
                            const float* __restrict__ mw,
                            const float* __restrict__ gw,
                            unsigned short* __restrict__ wp,
                            unsigned short* __restrict__ wn) {
  int idx = blockIdx.x * 512 + threadIdx.x;
  if (idx < N1) {
    int e = idx & 7, lane = (idx >> 3) & 63, ct = (idx >> 9) & 7, ks = (idx >> 12) & 3, t = idx >> 14;
    int l = t / 7, kw = t % 7;
    int co = ct * 16 + (lane & 15), ci = ks * 32 + (lane >> 4) * 8 + e;
    wp[idx] = f2h(w123[(((l * 128 + co) * 128) + ci) * 7 + kw]);
  } else if (idx < N1 + N2) {
    int k = idx - N1;
    int e = k & 7, lane = (k >> 3) & 63, ct = (k >> 9) & 7, ks = (k >> 12) & 3, t = k >> 14;
    int l = t / 3, kw = t % 3;
    int co = ct * 16 + (lane & 15), ci = ks * 32 + (lane >> 4) * 8 + e;
    wp[idx] = f2h(w4567[(((l * 128 + co) * 128) + ci) * 3 + kw]);
  } else if (idx < NTOT) {
    int k = idx - N1 - N2;
    int e = k & 7, lane = (k >> 3) & 63, ct = (k >> 9) & 15, ks = (k >> 13) & 3;
    int co = ct * 16 + (lane & 15), ci = ks * 32 + (lane >> 4) * 8 + e;
    wp[idx] = f2h(w8[co * 128 + ci]);
  } else if (idx < NTOT + NWN) {
    int k2 = idx - NTOT;
    int li = k2 >> 18, w = k2 & 262143;
    int e = w & 7, lane = (w >> 3) & 63, rt = (w >> 9) & 31, k32 = w >> 14;
    int row = rt * 16 + (lane & 15), k = k32 * 32 + (lane >> 4) * 8 + e;
    int ch = row >> 1, mat = row & 1, kw = k >> 8, ci = k & 255;
    const float* src = mat ? gw : mw;
    wn[k2] = f2h(src[(((size_t)li * 256 + ch) * 256 + ci) * 2 + kw]);
  }
}

// ---------------- direct-load MFMA conv layer, F=2 frames per block ----------------
// Each wave loads its A (weight) fragments ONCE and MFMAs them against BOTH frames'
// B fragments -> per-frame L2 weight traffic halves vs F=1.
template<int KW, int POFF, int PIN, int POUT, int MC, int MN, int OM>
__device__ __forceinline__ void mlayer_d2(const unsigned short* __restrict__ wp,
                                          const unsigned short* __restrict__ sin0,
                                          const unsigned short* __restrict__ sin1,
                                          unsigned short* __restrict__ sout0,
                                          unsigned short* __restrict__ sout1,
                                          unsigned short* __restrict__ gact,
                                          int tid, int frame0) {
  constexpr int HRIN = PIN / 2 + 4;
  constexpr int HROUT = POUT / 2 + 4;
  constexpr int Nt = (POUT + 15) / 16;
  constexpr int MNg = Nt / MN;
  constexpr int MCg = 8 / MNg;
  static_assert(MC * MCg == 8, "cout tiling must cover 128 channels");
  constexpr int NS = KW * 4;
  constexpr int DA = NS < 6 ? NS : 6;                      // deep A prefetch (L2 latency)
  constexpr int DB = NS < 3 ? NS : 3;

  const int wid = tid >> 6, lane = tid & 63, nl = lane & 15, q = lane >> 4;
  const int mcg = wid / MNg, mng = wid % MNg;
  const int ct0 = mcg * MC, nt0 = mng * MN;

  const unsigned short* sins[2] = {sin0, sin1};
  unsigned short* souts[2] = {sout0, sout1};

  int jj[MN]; bool val[MN]; int rofs[MN][KW];
#pragma unroll
  for (int jn = 0; jn < MN; ++jn) {
    int n = (nt0 + jn) * 16 + nl;
    val[jn] = (n < POUT);
    jj[jn] = val[jn] ? n : 0;
#pragma unroll
    for (int kw = 0; kw < KW; ++kw) {
      int P = 2 * jj[jn] + kw - POFF + 4;
      rofs[jn][kw] = ((P & 1) * HRIN + (P >> 1)) * RS + q * 8;
    }
  }
  const unsigned short* wl = wp + (size_t)ct0 * 512 + lane * 8;

  f32x4 acc[MC][MN][2];
#pragma unroll
  for (int i = 0; i < MC; ++i)
#pragma unroll
    for (int jn = 0; jn < MN; ++jn)
#pragma unroll
      for (int f = 0; f < 2; ++f) acc[i][jn][f] = (f32x4){0.f, 0.f, 0.f, 0.f};

  f16x8 A[DA][MC], B[DB][MN][2];
#pragma unroll
  for (int s = 0; s < DA; ++s)
#pragma unroll
    for (int i = 0; i < MC; ++i)
      A[s][i] = *(const f16x8*)(wl + (size_t)s * 4096 + i * 512);
#pragma unroll
  for (int s = 0; s < DB; ++s) {
    const int kw = s >> 2, ks = s & 3;
#pragma unroll
    for (int jn = 0; jn < MN; ++jn)
#pragma unroll
      for (int f = 0; f < 2; ++f)
        B[s][jn][f] = *(const f16x8*)(sins[f] + rofs[jn][kw] + ks * 32);
  }
#pragma unroll
  for (int s = 0; s < NS; ++s) {
    const int sa = s % DA, sb = s % DB;
#pragma unroll
    for (int i = 0; i < MC; ++i)
#pragma unroll
      for (int jn = 0; jn < MN; ++jn)
#pragma unroll
        for (int f = 0; f < 2; ++f)
          acc[i][jn][f] = __builtin_amdgcn_mfma_f32_16x16x32_f16(A[sa][i], B[sb][jn][f], acc[i][jn][f], 0, 0, 0);
    if (s + DA < NS) {
#pragma unroll
      for (int i = 0; i < MC; ++i)
        A[sa][i] = *(const f16x8*)(wl + (size_t)(s + DA) * 4096 + i * 512);
    }
    if (s + DB < NS) {
      const int kw = (s + DB) >> 2, ks = (s + DB) & 3;
#pragma unroll
      for (int jn = 0; jn < MN; ++jn)
#pragma unroll
        for (int f = 0; f < 2; ++f)
          B[sb][jn][f] = *(const f16x8*)(sins[f] + rofs[jn][kw] + ks * 32);
    }
  }

#pragma unroll
  for (int f = 0; f < 2; ++f) {
#pragma unroll
    for (int i = 0; i < MC; ++i) {
#pragma unroll
      for (int jn = 0; jn < MN; ++jn) {
        if (!val[jn]) continue;
        unsigned int lo = (unsigned)f2h(lrelu(acc[i][jn][f][0])) | ((unsigned)f2h(lrelu(acc[i][jn][f][1])) << 16);
        unsigned int hi = (unsigned)f2h(lrelu(acc[i][jn][f][2])) | ((unsigned)f2h(lrelu(acc[i][jn][f][3])) << 16);
        const int j = jj[jn];
        if (OM == 1) {
          *(uint2*)(gact + ((size_t)(frame0 + f) * POUT + j) * 128 + (ct0 + i) * 16 + q * 4) = make_uint2(lo, hi);
        } else {
          const int row = (j & 1) * HROUT + (j >> 1) + 2;
          *(uint2*)(souts[f] + (size_t)row * RS + (ct0 + i) * 16 + q * 4) = make_uint2(lo, hi);
        }
      }
    }
  }
  if (OM == 0) {
    constexpr int DEND = ((POUT - 1) >> 1) + 3;
    constexpr int NZ = 2 + (HROUT - DEND);
#pragma unroll
    for (int f = 0; f < 2; ++f) {
      unsigned int* zp = (unsigned int*)souts[f];
      for (int s2 = tid; s2 < 2 * NZ * 68; s2 += 512) {
        int col = s2 % 68, rr = s2 / 68;
        int par = rr / NZ, rz = rr % NZ;
        int row = rz < 2 ? rz : DEND + rz - 2;
        zp[((size_t)par * HROUT + row) * 68 + col] = 0;
      }
    }
    __syncthreads();
  }
}

// ---------------- E1: L0..L4, TWO frames per block, direct weight loads ----------------
__global__ __launch_bounds__(512, 2)
void encoder1(const float* __restrict__ x, const float* __restrict__ w0,
              const unsigned short* __restrict__ wp123,
              const unsigned short* __restrict__ wp4,
              unsigned short* __restrict__ act4g) {
  __shared__ __align__(16) unsigned short actA[2 * 18496]; // per-frame act0; later act2+act3
  __shared__ __align__(16) unsigned short actB[2 * 9792];  // per-frame act1; s_x overlaid pre-L1
  const int tid = threadIdx.x;
  const int frame0 = blockIdx.x * 2;
  const int bb = frame0 >> 8;                              // frames 2i,2i+1 share bb
  const int t0 = (frame0 & 255) + 256;

  float* s_x0 = (float*)actB;        // 262 floats
  float* s_x1 = (float*)actB + 272;  // 262 floats (16B-aligned offset)

  if (tid < 256) s_x0[3 + tid] = x[((bb << 8) + tid) * 512 + t0];
  else           s_x1[3 + (tid & 255)] = x[((bb << 8) + (tid & 255)) * 512 + t0 + 1];
  if (tid < 3)                 { s_x0[tid] = 0.f; s_x1[tid] = 0.f; }
  if (tid >= 259 && tid < 262) { s_x0[tid] = 0.f; s_x1[tid] = 0.f; }
  wait_lgkm0();
  bar();

  // L0: 1->128, k7 s2 p3 (fp32 VALU), both frames, store fp16 parity layout
  {
    const int c = tid & 127;
    const int sel = tid >> 7;          // j-chunk 0..3
    float wv[7];
#pragma unroll
    for (int k = 0; k < 7; ++k) wv[k] = w0[c * 7 + k];
#pragma unroll
    for (int f = 0; f < 2; ++f) {
      const float* sx = f ? s_x1 : s_x0;
      unsigned short* aA = actA + f * 18496;
      for (int j = sel * 32; j < sel * 32 + 32; ++j) {
        float s = 0.f;
#pragma unroll
        for (int k = 0; k < 7; ++k) s += wv[k] * sx[2 * j + k];
        int row = ((j & 1) ? 68 : 0) + (j >> 1) + 2;
        aA[row * RS + c] = f2h(lrelu(s));
      }
    }
#pragma unroll
    for (int f = 0; f < 2; ++f) {
      unsigned int* zp = (unsigned int*)(actA + f * 18496);
      for (int s2 = tid; s2 < 2 * 4 * 68; s2 += 512) {
        int col = s2 % 68;
        int rr = s2 / 68;
        int par = rr >> 2, r2 = rr & 3;
        int row = (r2 < 2) ? r2 : (64 + r2);
        zp[((size_t)par * 68 + row) * 68 + col] = 0;
      }
    }
  }
  wait_lgkm0();
  bar();

  mlayer_d2<7, 3, 128, 64, 2, 2, 0>(wp123,         actA, actA + 18496, actB, actB + 9792,
                                    nullptr, tid, frame0);                                   // L1
  mlayer_d2<7, 3, 64, 32, 1, 2, 0>(wp123 + 114688, actB, actB + 9792, actA, actA + 18496,
                                    nullptr, tid, frame0);                                   // L2
  mlayer_d2<7, 3, 32, 16, 1, 1, 0>(wp123 + 229376, actA, actA + 18496,
                                    actA + 5440, actA + 18496 + 5440, nullptr, tid, frame0); // L3
  mlayer_d2<3, 1, 16, 8, 1, 1, 1>(wp4,             actA + 5440, actA + 18496 + 5440,
                                    nullptr, nullptr, act4g, tid, frame0);                   // L4 -> global
}

// ---------------- generic MFMA conv layer (encoder2), frag-packed weights ----------------
template<int KW, int POFF, int PIN, int POUT, int FPB, int COUT, int MC, int MN, int OM, bool FLATIN>
__device__ __forceinline__ void mlayer(const unsigned short* __restrict__ wp,
                                       const unsigned short* __restrict__ sin_,
                                       unsigned short* __restrict__ sout,
                                       float* __restrict__ gout,
                                       int tid, int frame0) {
  constexpr int HRIN  = PIN / 2 + 4;
  constexpr int HROUT = POUT / 2 + 4;
  constexpr int NVAL = POUT * FPB;
  constexpr int Nt = (NVAL + 15) / 16;
  constexpr int Ct = COUT / 16;
  constexpr int MCg = Ct / MC, MNg = Nt / MN;
  constexpr int KS = 4;
  constexpr int NS = KW * KS;
  constexpr int DA = NS < 6 ? NS : 6;
  constexpr int DB = NS < 3 ? NS : 3;
  constexpr int L2P = POUT == 1 ? 0 : POUT == 2 ? 1 : POUT == 4 ? 2 : POUT == 8 ? 3 :
                      POUT == 16 ? 4 : POUT == 32 ? 5 : 6;

  const int wid = tid >> 6, lane = tid & 63, nl = lane & 15, q = lane >> 4;

  for (int mac = wid; mac < MCg * MNg; mac += 8) {
    const int mcg = mac / MNg, mng = mac % MNg;
    const int ct0 = mcg * MC, nt0 = mng * MN;
    int jj[MN]; bool val[MN];
#pragma unroll
    for (int jn = 0; jn < MN; ++jn) {
      int n = (nt0 + jn) * 16 + nl;
      val[jn] = (n < NVAL);
      jj[jn] = val[jn] ? n : 0;
    }
    int rofs[MN][KW];
#pragma unroll
    for (int jn = 0; jn < MN; ++jn) {
      const int f = jj[jn] >> L2P, j = jj[jn] & (POUT - 1);
#pragma unroll
      for (int kw = 0; kw < KW; ++kw) {
        if (FLATIN) {
          rofs[jn][kw] = jj[jn] * RS + q * 8;
        } else {
          int P = 2 * j + kw - POFF + 4;
          rofs[jn][kw] = (f * 2 * HRIN + (P & 1) * HRIN + (P >> 1)) * RS + q * 8;
        }
      }
    }
    int abase[MC];
#pragma unroll
    for (int i = 0; i < MC; ++i) abase[i] = (ct0 + i) * 512 + lane * 8;

    f32x4 acc[MC][MN];
#pragma unroll
    for (int i = 0; i < MC; ++i)
#pragma unroll
      for (int jn = 0; jn < MN; ++jn) acc[i][jn] = (f32x4){0.f, 0.f, 0.f, 0.f};

    f16x8 A[DA][MC], B[DB][MN];
#pragma unroll
    for (int s = 0; s < DA; ++s) {
      const int kw = s / KS, ks = s % KS;
#pragma unroll
      for (int i = 0; i < MC; ++i)
        A[s][i] = *(const f16x8*)(wp + (size_t)(kw * KS + ks) * (Ct * 512) + abase[i]);
    }
#pragma unroll
    for (int s = 0; s < DB; ++s) {
      const int kw = s / KS, ks = s % KS;
#pragma unroll
      for (int jn = 0; jn < MN; ++jn)
        B[s][jn] = *(const f16x8*)(sin_ + rofs[jn][kw] + ks * 32);
    }
#pragma unroll
    for (int s = 0; s < NS; ++s) {
      const int sa = s % DA, sb = s % DB;
#pragma unroll
      for (int i = 0; i < MC; ++i)
#pragma unroll
        for (int jn = 0; jn < MN; ++jn)
          acc[i][jn] = __builtin_amdgcn_mfma_f32_16x16x32_f16(A[sa][i], B[sb][jn], acc[i][jn], 0, 0, 0);
      if (s + DA < NS) {
        const int kw = (s + DA) / KS, ks = (s + DA) % KS;
#pragma unroll
        for (int i = 0; i < MC; ++i)
          A[sa][i] = *(const f16x8*)(wp + (size_t)(kw * KS + ks) * (Ct * 512) + abase[i]);
      }
      if (s + DB < NS) {
        const int kw = (s + DB) / KS, ks = (s + DB) % KS;
#pragma unroll
        for (int jn = 0; jn < MN; ++jn)
          B[sb][jn] = *(const f16x8*)(sin_ + rofs[jn][kw] + ks * 32);
      }
    }
#pragma unroll
    for (int i = 0; i < MC; ++i) {
#pragma unroll
      for (int jn = 0; jn < MN; ++jn) {
        if (OM == 3) {
          if (val[jn]) {
            const int frame = frame0 + jj[jn];   // POUT==1
            float4 v = make_float4(acc[i][jn][0], acc[i][jn][1], acc[i][jn][2], acc[i][jn][3]);
            *(float4*)(gout + (size_t)frame * 256 + (ct0 + i) * 16 + q * 4) = v;
          }
        } else if (OM == 2) {
          if (val[jn]) {
            unsigned int lo = (unsigned)f2h(lrelu(acc[i][jn][0])) | ((unsigned)f2h(lrelu(acc[i][jn][1])) << 16);
            unsigned int hi = (unsigned)f2h(lrelu(acc[i][jn][2])) | ((unsigned)f2h(lrelu(acc[i][jn][3])) << 16);
            *(uint2*)(sout + (size_t)jj[jn] * RS + (ct0 + i) * 16 + q * 4) = make_uint2(lo, hi);
          }
        } else {
          if (val[jn]) {
            const int f = jj[jn] >> L2P, j = jj[jn] & (POUT - 1);
            const int row = f * 2 * HROUT + (j & 1) * HROUT + (j >> 1) + 2;
            unsigned int lo = (unsigned)f2h(lrelu(acc[i][jn][0])) | ((unsigned)f2h(lrelu(acc[i][jn][1])) << 16);
            unsigned int hi = (unsigned)f2h(lrelu(acc[i][jn][2])) | ((unsigned)f2h(lrelu(acc[i][jn][3])) << 16);
            *(uint2*)(sout + (size_t)row * RS + (ct0 + i) * 16 + q * 4) = make_uint2(lo, hi);
          }
        }
      }
    }
  }
  if (OM == 0) {
    constexpr int DEND = ((POUT - 1) >> 1) + 3;
    constexpr int NZ = 2 + (HROUT - DEND);
    constexpr int TOTU = FPB * 2 * NZ * (RS / 2);
    unsigned int* zp = (unsigned int*)sout;
    for (int s2 = tid; s2 < TOTU; s2 += 512) {
      int col = s2 % 68;
      int rr = s2 / 68;
      int fr = rr / (2 * NZ), r2 = rr % (2 * NZ);
      int par = r2 / NZ, rz = r2 % NZ;
      int row = rz < 2 ? rz : DEND + rz - 2;
      zp[((size_t)(fr * 2 + par) * HROUT + row) * 68 + col] = 0;
    }
    __syncthreads();
  } else if (OM == 2) {
    __syncthreads();
  }
}

// ---------------- E2: L5..L8, 8 frames per block ----------------
__global__ __launch_bounds__(512)
void encoder2(const unsigned short* __restrict__ act4g,
              const unsigned short* __restrict__ wp4,
              const unsigned short* __restrict__ wp8,
              float* __restrict__ h) {
  __shared__ __align__(16) unsigned short actP[17408];
  __shared__ __align__(16) unsigned short actQ[13056];
  __shared__ __align__(16) unsigned short actR[2176];
  const int tid = threadIdx.x;
  const int frame0 = blockIdx.x * 8;

  {
    uint4 z4 = make_uint4(0, 0, 0, 0);
    for (int s = tid; s < 2176; s += 512) ((uint4*)actP)[s] = z4;
    for (int s = tid; s < 1632; s += 512) ((uint4*)actQ)[s] = z4;
    for (int s = tid; s < 272; s += 512) ((uint4*)actR)[s] = z4;
  }
  __syncthreads();
  for (int c = tid; c < 1024; c += 512) {
    int f = c >> 7, rem = c & 127, pos = rem >> 4, o = (rem & 15) * 8;
    uint4 v = *(const uint4*)(act4g + ((size_t)(frame0 + f) * 8 + pos) * 128 + o);
    int P = pos + 4;
    int row = (P & 1) * 8 + (P >> 1);
    *(uint4*)(actP + ((size_t)f * 16 + row) * RS + o) = v;
  }
  __syncthreads();

  mlayer<3, 1, 8, 4, 8, 128, 2, 1, 0, false>(wp4 + 49152,  actP, actQ, nullptr, tid, frame0);  // L5
  mlayer<3, 1, 4, 2, 8, 128, 1, 1, 0, false>(wp4 + 98304,  actQ, actP, nullptr, tid, frame0);  // L6
  mlayer<3, 1, 2, 1, 8, 128, 1, 1, 2, false>(wp4 + 147456, actP, actR, nullptr, tid, frame0);  // L7 flat
  mlayer<1, 0, 1, 1, 8, 256, 1, 1, 3, true>(wp8,           actR, nullptr, h, tid, frame0);     // L8 -> h fp32
}

// ---------------- WaveNet fused layer, all li; finalize fused at li==7 ----------------
__global__ __launch_bounds__(256)
void wnet_kernel(const unsigned short* __restrict__ wn,
                 const float* __restrict__ hsrc, float* __restrict__ hdst,
                 float* __restrict__ feats, const float* __restrict__ jw,
                 float* __restrict__ out, int li) {
  const int npos = 128 >> li, p = 1 << li, N = npos * 8, lnp = 7 - li;
  const int tid = threadIdx.x;
  const int nb = blockIdx.x >> 2, mb = blockIdx.x & 3;
  const int n0 = nb * 16;
  __shared__ __align__(16) unsigned short sB[16 * 520];
  __shared__ float jls[8];

  for (int c = tid; c < 1024; c += 256) {
    const int nr = c >> 6, o = (c & 63) * 8;
    const int n = n0 + nr;
    unsigned short tmp[8] = {0, 0, 0, 0, 0, 0, 0, 0};
    if (n < N) {
      const int b = n >> lnp, kk = n & (npos - 1);
      const int t = 255 - (kk << (li + 1));
      const float* src = (o < 256) ? hsrc + ((size_t)(b * 256 + t - p)) * 256 + o
                                   : hsrc + ((size_t)(b * 256 + t)) * 256 + (o - 256);
      float4 v0 = *(const float4*)(src);
      float4 v1 = *(const float4*)(src + 4);
      tmp[0] = f2h(v0.x); tmp[1] = f2h(v0.y); tmp[2] = f2h(v0.z); tmp[3] = f2h(v0.w);
      tmp[4] = f2h(v1.x); tmp[5] = f2h(v1.y); tmp[6] = f2h(v1.z); tmp[7] = f2h(v1.w);
    }
    unsigned int u0 = (unsigned)tmp[0] | ((unsigned)tmp[1] << 16);
    unsigned int u1 = (unsigned)tmp[2] | ((unsigned)tmp[3] << 16);
    unsigned int u2 = (unsigned)tmp[4] | ((unsigned)tmp[5] << 16);
    unsigned int u3 = (unsigned)tmp[6] | ((unsigned)tmp[7] << 16);
    *(uint4*)(sB + (size_t)nr * 520 + o) = make_uint4(u0, u1, u2, u3);
  }
  __syncthreads();

  const int wid = tid >> 6, lane = tid & 63, nl = lane & 15, q = lane >> 4;
  f32x4 acc[2];
  acc[0] = (f32x4){0.f, 0.f, 0.f, 0.f};
  acc[1] = (f32x4){0.f, 0.f, 0.f, 0.f};
  int arow[2];
#pragma unroll
  for (int i = 0; i < 2; ++i) arow[i] = (mb * 8 + wid * 2 + i) * 512 + lane * 8;
  const int bofs = nl * 520 + q * 8;

  f16x8 A[4][2], Bv[2];
#pragma unroll
  for (int s = 0; s < 4; ++s)
#pragma unroll
    for (int i = 0; i < 2; ++i) A[s][i] = *(const f16x8*)(wn + arow[i] + (size_t)s * 16384);
#pragma unroll
  for (int s = 0; s < 2; ++s) Bv[s] = *(const f16x8*)(sB + bofs + s * 32);
#pragma unroll
  for (int s = 0; s < 16; ++s) {
    const int sa = s & 3, sb = s & 1;
    acc[0] = __builtin_amdgcn_mfma_f32_16x16x32_f16(A[sa][0], Bv[sb], acc[0], 0, 0, 0);
    acc[1] = __builtin_amdgcn_mfma_f32_16x16x32_f16(A[sa][1], Bv[sb], acc[1], 0, 0, 0);
    if (s + 4 < 16) {
#pragma unroll
      for (int i = 0; i < 2; ++i) A[sa][i] = *(const f16x8*)(wn + arow[i] + (size_t)(s + 4) * 16384);
    }
    if (s + 2 < 16) Bv[sb] = *(const f16x8*)(sB + bofs + (s + 2) * 32);
  }

  const int n = n0 + nl;
  if (li < 7) {
    if (n < N) {
      const int b = n >> lnp, kk = n & (npos - 1);
      const int t = 255 - (kk << (li + 1));
      const size_t rowoff = ((size_t)(b * 256 + t)) * 256;
#pragma unroll
      for (int i = 0; i < 2; ++i) {
        const int ch = mb * 64 + (wid * 2 + i) * 8 + q * 2;
        const float z0 = tanhf(acc[i][0]) * (1.f / (1.f + expf(-acc[i][1])));
        const float z1 = tanhf(acc[i][2]) * (1.f / (1.f + expf(-acc[i][3])));
        float2 hv = *(const float2*)(hsrc + rowoff + ch);
        *(float2*)(hdst + rowoff + ch) = make_float2(hv.x + z0, hv.y + z1);
        if (kk == 0) {
          float* fp = feats + b * 256 + ch;
          if (li == 0) { fp[0] = z0; fp[1] = z1; }
          else         { fp[0] += z0; fp[1] += z1; }
        }
      }
    }
  } else {
    // li == 7: final layer + fused finalize. 4 blocks (mb), each covers all 8
    // batches (n = nl < 8) and 64 output channels. j partials via LDS + global atomics.
    if (tid < 8) jls[tid] = 0.f;
    __syncthreads();
    if (n < N) {
      const int b = n;                    // lnp == 0, kk == 0, t == 255
      float partial = 0.f;
#pragma unroll
      for (int i = 0; i < 2; ++i) {
        const int ch = mb * 64 + (wid * 2 + i) * 8 + q * 2;
        const float z0 = tanhf(acc[i][0]) * (1.f / (1.f + expf(-acc[i][1])));
        const float z1 = tanhf(acc[i][2]) * (1.f / (1.f + expf(-acc[i][3])));
        const float* fp = feats + b * 256 + ch;
        const float f0 = fp[0] + z0;
        const float f1 = fp[1] + z1;
        *(float2*)(out + b * 256 + ch) = make_float2(f0, f1);
        partial += f0 * jw[ch] + f1 * jw[ch + 1];
      }
      atomicAdd(&jls[b], partial);
    }
    __syncthreads();
    if (tid < 8) atomicAdd(out + NB * 256 + tid, jls[tid]);
  }
}

extern "C" void kernel_launch(void* const* d_in, const int* in_sizes, int n_in,
                              void* d_out, int out_size, void* d_ws, size_t ws_size,
                              hipStream_t stream) {
  const float* x     = (const float*)d_in[0];
  const float* w0    = (const float*)d_in[1];
  const float* w123  = (const float*)d_in[2];
  const float* w4567 = (const float*)d_in[3];
  const float* w8    = (const float*)d_in[4];
  const float* mw    = (const float*)d_in[5];
  const float* gw    = (const float*)d_in[6];
  const float* jw    = (const float*)d_in[7];
  float* out = (float*)d_out;

  float* ws = (float*)d_ws;
  unsigned short* act4g = (unsigned short*)ws;            // 2,097,152 fp16
  float* h0    = ws + 1048576;                            // 524,288 f
  float* h1    = ws + 1572864;                            // 524,288 f
  float* feats = ws + 2097152;                            // 2,048 f
  unsigned short* wp = (unsigned short*)(ws + 2099200);   // 573,440 fp16
  unsigned short* wn = (unsigned short*)(ws + 2385920);   // 2,097,152 fp16

  hipMemsetAsync(out + NB * 256, 0, NB * sizeof(float), stream);  // j accumulator slots
  pack_kernel<<<5216, 512, 0, stream>>>(w123, w4567, w8, mw, gw, wp, wn);
  encoder1<<<1024, 512, 0, stream>>>(x, w0, wp, wp + N1, act4g);
  encoder2<<<256, 512, 0, stream>>>(act4g, wp + N1, wp + N1 + N2, h0);

  float* hs = h0; float* hd = h1;
  for (int i = 0; i < 8; ++i) {
    const unsigned short* wl = wn + (size_t)i * 262144;
    const int N = (128 >> i) * 8;
    const int nN = (N + 15) / 16;
    wnet_kernel<<<4 * nN, 256, 0, stream>>>(wl, hs, hd, feats, jw, out, i);
    float* tmp = hd; hd = hs; hs = tmp;
  }
}

// Round 7
// 207.675 us; speedup vs baseline: 2.9836x; 1.0241x over previous
//
#include <hip/hip_runtime.h>
#include <math.h>

#define FC 256
#define NB 8
#define RS 136   // encoder2 LDS act row stride in fp16 elems (128 ci + 8 pad)

typedef __attribute__((ext_vector_type(8))) _Float16 f16x8;
typedef __attribute__((ext_vector_type(4))) float f32x4;

__device__ __forceinline__ float lrelu(float v) { return fmaxf(v, 0.2f * v); }
__device__ __forceinline__ unsigned short f2h(float f) {
  _Float16 h = (_Float16)f;
  return *(unsigned short*)&h;
}
__device__ __forceinline__ void bar() { asm volatile("s_barrier" ::: "memory"); }
__device__ __forceinline__ void wait_lgkm0() { asm volatile("s_waitcnt lgkmcnt(0)" ::: "memory"); }

// ---------------- weight pack: fp32 -> fp16, MFMA A-fragment layout ----------------
#define N1 344064   // 3*7*128*128   enc w123
#define N2 196608   // 4*3*128*128   enc w4567
#define N3 32768    // 256*128       enc w8 (Ct=16)
#define NTOT 573440
#define NWN 2097152 // 8*512*512     wnet

__global__ void pack_kernel(const float* __restrict__ w123,
                            const float* __restrict__ w4567,
                            const float* __restrict__ w8,
                            const float* __restrict__ mw,
                            const float* __restrict__ gw,
                            unsigned short* __restrict__ wp,
                            unsigned short* __restrict__ wn) {
  int idx = blockIdx.x * 512 + threadIdx.x;
  if (idx < N1) {
    int e = idx & 7, lane = (idx >> 3) & 63, ct = (idx >> 9) & 7, ks = (idx >> 12) & 3, t = idx >> 14;
    int l = t / 7, kw = t % 7;
    int co = ct * 16 + (lane & 15), ci = ks * 32 + (lane >> 4) * 8 + e;
    wp[idx] = f2h(w123[(((l * 128 + co) * 128) + ci) * 7 + kw]);
  } else if (idx < N1 + N2) {
    int k = idx - N1;
    int e = k & 7, lane = (k >> 3) & 63, ct = (k >> 9) & 7, ks = (k >> 12) & 3, t = k >> 14;
    int l = t / 3, kw = t % 3;
    int co = ct * 16 + (lane & 15), ci = ks * 32 + (lane >> 4) * 8 + e;
    wp[idx] = f2h(w4567[(((l * 128 + co) * 128) + ci) * 3 + kw]);
  } else if (idx < NTOT) {
    int k = idx - N1 - N2;
    int e = k & 7, lane = (k >> 3) & 63, ct = (k >> 9) & 15, ks = (k >> 13) & 3;
    int co = ct * 16 + (lane & 15), ci = ks * 32 + (lane >> 4) * 8 + e;
    wp[idx] = f2h(w8[co * 128 + ci]);
  } else if (idx < NTOT + NWN) {
    int k2 = idx - NTOT;
    int li = k2 >> 18, w = k2 & 262143;
    int e = w & 7, lane = (w >> 3) & 63, rt = (w >> 9) & 31, k32 = w >> 14;
    int row = rt * 16 + (lane & 15), k = k32 * 32 + (lane >> 4) * 8 + e;
    int ch = row >> 1, mat = row & 1, kw = k >> 8, ci = k & 255;
    const float* src = mat ? gw : mw;
    wn[k2] = f2h(src[(((size_t)li * 256 + ch) * 256 + ci) * 2 + kw]);
  }
}

// ---------------- direct-load MFMA conv layer, F=2 frames, XOR-swizzled LDS ----------------
// LDS layout: row stride 128 halves (256B), 16B block index XORed with (row&7)
// (T2 / G4 fix: lanes read different rows at same column slice -> conflict-free).
template<int KW, int POFF, int PIN, int POUT, int MC, int MN, int OM>
__device__ __forceinline__ void mlayer_d2(const unsigned short* __restrict__ wp,
                                          const unsigned short* __restrict__ sin0,
                                          const unsigned short* __restrict__ sin1,
                                          unsigned short* __restrict__ sout0,
                                          unsigned short* __restrict__ sout1,
                                          unsigned short* __restrict__ gact,
                                          int tid, int frame0) {
  constexpr int HRIN = PIN / 2 + 4;
  constexpr int HROUT = POUT / 2 + 4;
  constexpr int Nt = (POUT + 15) / 16;
  constexpr int MNg = Nt / MN;
  constexpr int MCg = 8 / MNg;
  static_assert(MC * MCg == 8, "cout tiling must cover 128 channels");
  constexpr int NS = KW * 4;
  constexpr int DA = NS < 6 ? NS : 6;
  constexpr int DB = NS < 3 ? NS : 3;

  const int wid = tid >> 6, lane = tid & 63, nl = lane & 15, q = lane >> 4;
  const int q8 = q * 8;
  const int mcg = wid / MNg, mng = wid % MNg;
  const int ct0 = mcg * MC, nt0 = mng * MN;

  const unsigned short* sins[2] = {sin0, sin1};
  unsigned short* souts[2] = {sout0, sout1};

  int jj[MN]; bool val[MN]; int rb[MN][KW]; int rx[MN][KW];
#pragma unroll
  for (int jn = 0; jn < MN; ++jn) {
    int n = (nt0 + jn) * 16 + nl;
    val[jn] = (n < POUT);
    jj[jn] = val[jn] ? n : 0;
#pragma unroll
    for (int kw = 0; kw < KW; ++kw) {
      int P = 2 * jj[jn] + kw - POFF + 4;
      int row = (P & 1) * HRIN + (P >> 1);
      rb[jn][kw] = row * 128;
      rx[jn][kw] = (row & 7) << 3;
    }
  }
  const unsigned short* wl = wp + (size_t)ct0 * 512 + lane * 8;

  f32x4 acc[MC][MN][2];
#pragma unroll
  for (int i = 0; i < MC; ++i)
#pragma unroll
    for (int jn = 0; jn < MN; ++jn)
#pragma unroll
      for (int f = 0; f < 2; ++f) acc[i][jn][f] = (f32x4){0.f, 0.f, 0.f, 0.f};

  f16x8 A[DA][MC], B[DB][MN][2];
#pragma unroll
  for (int s = 0; s < DA; ++s)
#pragma unroll
    for (int i = 0; i < MC; ++i)
      A[s][i] = *(const f16x8*)(wl + (size_t)s * 4096 + i * 512);
#pragma unroll
  for (int s = 0; s < DB; ++s) {
    const int kw = s >> 2, ks = s & 3;
#pragma unroll
    for (int jn = 0; jn < MN; ++jn)
#pragma unroll
      for (int f = 0; f < 2; ++f)
        B[s][jn][f] = *(const f16x8*)(sins[f] + rb[jn][kw] + ((ks * 32 + q8) ^ rx[jn][kw]));
  }
#pragma unroll
  for (int s = 0; s < NS; ++s) {
    const int sa = s % DA, sb = s % DB;
#pragma unroll
    for (int i = 0; i < MC; ++i)
#pragma unroll
      for (int jn = 0; jn < MN; ++jn)
#pragma unroll
        for (int f = 0; f < 2; ++f)
          acc[i][jn][f] = __builtin_amdgcn_mfma_f32_16x16x32_f16(A[sa][i], B[sb][jn][f], acc[i][jn][f], 0, 0, 0);
    if (s + DA < NS) {
#pragma unroll
      for (int i = 0; i < MC; ++i)
        A[sa][i] = *(const f16x8*)(wl + (size_t)(s + DA) * 4096 + i * 512);
    }
    if (s + DB < NS) {
      const int kw = (s + DB) >> 2, ks = (s + DB) & 3;
#pragma unroll
      for (int jn = 0; jn < MN; ++jn)
#pragma unroll
        for (int f = 0; f < 2; ++f)
          B[sb][jn][f] = *(const f16x8*)(sins[f] + rb[jn][kw] + ((ks * 32 + q8) ^ rx[jn][kw]));
    }
  }

#pragma unroll
  for (int f = 0; f < 2; ++f) {
#pragma unroll
    for (int i = 0; i < MC; ++i) {
#pragma unroll
      for (int jn = 0; jn < MN; ++jn) {
        if (!val[jn]) continue;
        unsigned int lo = (unsigned)f2h(lrelu(acc[i][jn][f][0])) | ((unsigned)f2h(lrelu(acc[i][jn][f][1])) << 16);
        unsigned int hi = (unsigned)f2h(lrelu(acc[i][jn][f][2])) | ((unsigned)f2h(lrelu(acc[i][jn][f][3])) << 16);
        const int j = jj[jn];
        if (OM == 1) {
          *(uint2*)(gact + ((size_t)(frame0 + f) * POUT + j) * 128 + (ct0 + i) * 16 + q * 4) = make_uint2(lo, hi);
        } else {
          const int row = (j & 1) * HROUT + (j >> 1) + 2;
          const int off = row * 128 + (((ct0 + i) * 16 + (q >> 1) * 8) ^ ((row & 7) << 3)) + (q & 1) * 4;
          *(uint2*)(souts[f] + off) = make_uint2(lo, hi);
        }
      }
    }
  }
  if (OM == 0) {
    constexpr int DEND = ((POUT - 1) >> 1) + 3;
    constexpr int NZ = 2 + (HROUT - DEND);
#pragma unroll
    for (int f = 0; f < 2; ++f) {
      unsigned int* zp = (unsigned int*)souts[f];
      for (int s2 = tid; s2 < 2 * NZ * 64; s2 += 512) {
        int col = s2 & 63, rr = s2 >> 6;
        int par = rr / NZ, rz = rr % NZ;
        int row = rz < 2 ? rz : DEND + rz - 2;
        zp[((par * HROUT + row) << 6) + col] = 0;   // whole-row zero: swizzle-invariant
      }
    }
    __syncthreads();
  }
}

// ---------------- E1: L0..L4, TWO frames per block, swizzled act LDS ----------------
__global__ __launch_bounds__(512, 2)
void encoder1(const float* __restrict__ x, const float* __restrict__ w0,
              const unsigned short* __restrict__ wp123,
              const unsigned short* __restrict__ wp4,
              unsigned short* __restrict__ act4g) {
  __shared__ __align__(16) unsigned short actA[34816];  // 2 frames x act0 (2*68 rows x 128); later act2/act3
  __shared__ __align__(16) unsigned short actB[18432];  // 2 frames x act1 (2*36 rows x 128); s_x overlay
  const int tid = threadIdx.x;
  const int frame0 = blockIdx.x * 2;
  const int bb = frame0 >> 8;
  const int t0 = (frame0 & 255) + 256;

  float* s_x0 = (float*)actB;        // 262 floats
  float* s_x1 = (float*)actB + 272;  // 262 floats

  if (tid < 256) s_x0[3 + tid] = x[((bb << 8) + tid) * 512 + t0];
  else           s_x1[3 + (tid & 255)] = x[((bb << 8) + (tid & 255)) * 512 + t0 + 1];
  if (tid < 3)                 { s_x0[tid] = 0.f; s_x1[tid] = 0.f; }
  if (tid >= 259 && tid < 262) { s_x0[tid] = 0.f; s_x1[tid] = 0.f; }
  wait_lgkm0();
  bar();

  // L0: 1->128, k7 s2 p3 (fp32 VALU), both frames, swizzled parity layout
  {
    const int c = tid & 127;
    const int sel = tid >> 7;
    const int cblk = c & 120, clo = c & 7;
    float wv[7];
#pragma unroll
    for (int k = 0; k < 7; ++k) wv[k] = w0[c * 7 + k];
#pragma unroll
    for (int f = 0; f < 2; ++f) {
      const float* sx = f ? s_x1 : s_x0;
      unsigned short* aA = actA + f * 17408;
      for (int j = sel * 32; j < sel * 32 + 32; ++j) {
        float s = 0.f;
#pragma unroll
        for (int k = 0; k < 7; ++k) s += wv[k] * sx[2 * j + k];
        int row = ((j & 1) ? 68 : 0) + (j >> 1) + 2;
        aA[row * 128 + (cblk ^ ((row & 7) << 3)) + clo] = f2h(lrelu(s));
      }
    }
#pragma unroll
    for (int f = 0; f < 2; ++f) {
      unsigned int* zp = (unsigned int*)(actA + f * 17408);
      for (int s2 = tid; s2 < 2 * 4 * 64; s2 += 512) {
        int col = s2 & 63;
        int rr = s2 >> 6;
        int par = rr >> 2, r2 = rr & 3;
        int row = (r2 < 2) ? r2 : (64 + r2);
        zp[((par * 68 + row) << 6) + col] = 0;
      }
    }
  }
  wait_lgkm0();
  bar();

  mlayer_d2<7, 3, 128, 64, 2, 2, 0>(wp123,         actA, actA + 17408, actB, actB + 9216,
                                    nullptr, tid, frame0);                                   // L1
  mlayer_d2<7, 3, 64, 32, 1, 2, 0>(wp123 + 114688, actB, actB + 9216, actA, actA + 17408,
                                    nullptr, tid, frame0);                                   // L2
  mlayer_d2<7, 3, 32, 16, 1, 1, 0>(wp123 + 229376, actA, actA + 17408,
                                    actA + 5120, actA + 17408 + 5120, nullptr, tid, frame0); // L3
  mlayer_d2<3, 1, 16, 8, 1, 1, 1>(wp4,             actA + 5120, actA + 17408 + 5120,
                                    nullptr, nullptr, act4g, tid, frame0);                   // L4 -> global
}

// ---------------- generic MFMA conv layer (encoder2), frag-packed weights ----------------
template<int KW, int POFF, int PIN, int POUT, int FPB, int COUT, int MC, int MN, int OM, bool FLATIN>
__device__ __forceinline__ void mlayer(const unsigned short* __restrict__ wp,
                                       const unsigned short* __restrict__ sin_,
                                       unsigned short* __restrict__ sout,
                                       float* __restrict__ gout,
                                       int tid, int frame0) {
  constexpr int HRIN  = PIN / 2 + 4;
  constexpr int HROUT = POUT / 2 + 4;
  constexpr int NVAL = POUT * FPB;
  constexpr int Nt = (NVAL + 15) / 16;
  constexpr int Ct = COUT / 16;
  constexpr int MCg = Ct / MC, MNg = Nt / MN;
  constexpr int KS = 4;
  constexpr int NS = KW * KS;
  constexpr int DA = NS < 6 ? NS : 6;
  constexpr int DB = NS < 3 ? NS : 3;
  constexpr int L2P = POUT == 1 ? 0 : POUT == 2 ? 1 : POUT == 4 ? 2 : POUT == 8 ? 3 :
                      POUT == 16 ? 4 : POUT == 32 ? 5 : 6;

  const int wid = tid >> 6, lane = tid & 63, nl = lane & 15, q = lane >> 4;

  for (int mac = wid; mac < MCg * MNg; mac += 8) {
    const int mcg = mac / MNg, mng = mac % MNg;
    const int ct0 = mcg * MC, nt0 = mng * MN;
    int jj[MN]; bool val[MN];
#pragma unroll
    for (int jn = 0; jn < MN; ++jn) {
      int n = (nt0 + jn) * 16 + nl;
      val[jn] = (n < NVAL);
      jj[jn] = val[jn] ? n : 0;
    }
    int rofs[MN][KW];
#pragma unroll
    for (int jn = 0; jn < MN; ++jn) {
      const int f = jj[jn] >> L2P, j = jj[jn] & (POUT - 1);
#pragma unroll
      for (int kw = 0; kw < KW; ++kw) {
        if (FLATIN) {
          rofs[jn][kw] = jj[jn] * RS + q * 8;
        } else {
          int P = 2 * j + kw - POFF + 4;
          rofs[jn][kw] = (f * 2 * HRIN + (P & 1) * HRIN + (P >> 1)) * RS + q * 8;
        }
      }
    }
    int abase[MC];
#pragma unroll
    for (int i = 0; i < MC; ++i) abase[i] = (ct0 + i) * 512 + lane * 8;

    f32x4 acc[MC][MN];
#pragma unroll
    for (int i = 0; i < MC; ++i)
#pragma unroll
      for (int jn = 0; jn < MN; ++jn) acc[i][jn] = (f32x4){0.f, 0.f, 0.f, 0.f};

    f16x8 A[DA][MC], B[DB][MN];
#pragma unroll
    for (int s = 0; s < DA; ++s) {
      const int kw = s / KS, ks = s % KS;
#pragma unroll
      for (int i = 0; i < MC; ++i)
        A[s][i] = *(const f16x8*)(wp + (size_t)(kw * KS + ks) * (Ct * 512) + abase[i]);
    }
#pragma unroll
    for (int s = 0; s < DB; ++s) {
      const int kw = s / KS, ks = s % KS;
#pragma unroll
      for (int jn = 0; jn < MN; ++jn)
        B[s][jn] = *(const f16x8*)(sin_ + rofs[jn][kw] + ks * 32);
    }
#pragma unroll
    for (int s = 0; s < NS; ++s) {
      const int sa = s % DA, sb = s % DB;
#pragma unroll
      for (int i = 0; i < MC; ++i)
#pragma unroll
        for (int jn = 0; jn < MN; ++jn)
          acc[i][jn] = __builtin_amdgcn_mfma_f32_16x16x32_f16(A[sa][i], B[sb][jn], acc[i][jn], 0, 0, 0);
      if (s + DA < NS) {
        const int kw = (s + DA) / KS, ks = (s + DA) % KS;
#pragma unroll
        for (int i = 0; i < MC; ++i)
          A[sa][i] = *(const f16x8*)(wp + (size_t)(kw * KS + ks) * (Ct * 512) + abase[i]);
      }
      if (s + DB < NS) {
        const int kw = (s + DB) / KS, ks = (s + DB) % KS;
#pragma unroll
        for (int jn = 0; jn < MN; ++jn)
          B[sb][jn] = *(const f16x8*)(sin_ + rofs[jn][kw] + ks * 32);
      }
    }
#pragma unroll
    for (int i = 0; i < MC; ++i) {
#pragma unroll
      for (int jn = 0; jn < MN; ++jn) {
        if (OM == 3) {
          if (val[jn]) {
            const int frame = frame0 + jj[jn];   // POUT==1
            float4 v = make_float4(acc[i][jn][0], acc[i][jn][1], acc[i][jn][2], acc[i][jn][3]);
            *(float4*)(gout + (size_t)frame * 256 + (ct0 + i) * 16 + q * 4) = v;
          }
        } else if (OM == 2) {
          if (val[jn]) {
            unsigned int lo = (unsigned)f2h(lrelu(acc[i][jn][0])) | ((unsigned)f2h(lrelu(acc[i][jn][1])) << 16);
            unsigned int hi = (unsigned)f2h(lrelu(acc[i][jn][2])) | ((unsigned)f2h(lrelu(acc[i][jn][3])) << 16);
            *(uint2*)(sout + (size_t)jj[jn] * RS + (ct0 + i) * 16 + q * 4) = make_uint2(lo, hi);
          }
        } else {
          if (val[jn]) {
            const int f = jj[jn] >> L2P, j = jj[jn] & (POUT - 1);
            const int row = f * 2 * HROUT + (j & 1) * HROUT + (j >> 1) + 2;
            unsigned int lo = (unsigned)f2h(lrelu(acc[i][jn][0])) | ((unsigned)f2h(lrelu(acc[i][jn][1])) << 16);
            unsigned int hi = (unsigned)f2h(lrelu(acc[i][jn][2])) | ((unsigned)f2h(lrelu(acc[i][jn][3])) << 16);
            *(uint2*)(sout + (size_t)row * RS + (ct0 + i) * 16 + q * 4) = make_uint2(lo, hi);
          }
        }
      }
    }
  }
  if (OM == 0) {
    constexpr int DEND = ((POUT - 1) >> 1) + 3;
    constexpr int NZ = 2 + (HROUT - DEND);
    constexpr int TOTU = FPB * 2 * NZ * (RS / 2);
    unsigned int* zp = (unsigned int*)sout;
    for (int s2 = tid; s2 < TOTU; s2 += 512) {
      int col = s2 % 68;
      int rr = s2 / 68;
      int fr = rr / (2 * NZ), r2 = rr % (2 * NZ);
      int par = r2 / NZ, rz = r2 % NZ;
      int row = rz < 2 ? rz : DEND + rz - 2;
      zp[((size_t)(fr * 2 + par) * HROUT + row) * 68 + col] = 0;
    }
    __syncthreads();
  } else if (OM == 2) {
    __syncthreads();
  }
}

// ---------------- E2: L5..L8, 8 frames per block ----------------
__global__ __launch_bounds__(512)
void encoder2(const unsigned short* __restrict__ act4g,
              const unsigned short* __restrict__ wp4,
              const unsigned short* __restrict__ wp8,
              float* __restrict__ h) {
  __shared__ __align__(16) unsigned short actP[17408];
  __shared__ __align__(16) unsigned short actQ[13056];
  __shared__ __align__(16) unsigned short actR[2176];
  const int tid = threadIdx.x;
  const int frame0 = blockIdx.x * 8;

  {
    uint4 z4 = make_uint4(0, 0, 0, 0);
    for (int s = tid; s < 2176; s += 512) ((uint4*)actP)[s] = z4;
    for (int s = tid; s < 1632; s += 512) ((uint4*)actQ)[s] = z4;
    for (int s = tid; s < 272; s += 512) ((uint4*)actR)[s] = z4;
  }
  __syncthreads();
  for (int c = tid; c < 1024; c += 512) {
    int f = c >> 7, rem = c & 127, pos = rem >> 4, o = (rem & 15) * 8;
    uint4 v = *(const uint4*)(act4g + ((size_t)(frame0 + f) * 8 + pos) * 128 + o);
    int P = pos + 4;
    int row = (P & 1) * 8 + (P >> 1);
    *(uint4*)(actP + ((size_t)f * 16 + row) * RS + o) = v;
  }
  __syncthreads();

  mlayer<3, 1, 8, 4, 8, 128, 2, 1, 0, false>(wp4 + 49152,  actP, actQ, nullptr, tid, frame0);  // L5
  mlayer<3, 1, 4, 2, 8, 128, 1, 1, 0, false>(wp4 + 98304,  actQ, actP, nullptr, tid, frame0);  // L6
  mlayer<3, 1, 2, 1, 8, 128, 1, 1, 2, false>(wp4 + 147456, actP, actR, nullptr, tid, frame0);  // L7 flat
  mlayer<1, 0, 1, 1, 8, 256, 1, 1, 3, true>(wp8,           actR, nullptr, h, tid, frame0);     // L8 -> h fp32
}

// ---------------- WaveNet fused layer, all li; finalize fused at li==7 ----------------
__global__ __launch_bounds__(256)
void wnet_kernel(const unsigned short* __restrict__ wn,
                 const float* __restrict__ hsrc, float* __restrict__ hdst,
                 float* __restrict__ feats, const float* __restrict__ jw,
                 float* __restrict__ out, int li) {
  const int npos = 128 >> li, p = 1 << li, N = npos * 8, lnp = 7 - li;
  const int tid = threadIdx.x;
  const int nb = blockIdx.x >> 2, mb = blockIdx.x & 3;
  const int n0 = nb * 16;
  __shared__ __align__(16) unsigned short sB[16 * 520];
  __shared__ float jls[8];

  for (int c = tid; c < 1024; c += 256) {
    const int nr = c >> 6, o = (c & 63) * 8;
    const int n = n0 + nr;
    unsigned short tmp[8] = {0, 0, 0, 0, 0, 0, 0, 0};
    if (n < N) {
      const int b = n >> lnp, kk = n & (npos - 1);
      const int t = 255 - (kk << (li + 1));
      const float* src = (o < 256) ? hsrc + ((size_t)(b * 256 + t - p)) * 256 + o
                                   : hsrc + ((size_t)(b * 256 + t)) * 256 + (o - 256);
      float4 v0 = *(const float4*)(src);
      float4 v1 = *(const float4*)(src + 4);
      tmp[0] = f2h(v0.x); tmp[1] = f2h(v0.y); tmp[2] = f2h(v0.z); tmp[3] = f2h(v0.w);
      tmp[4] = f2h(v1.x); tmp[5] = f2h(v1.y); tmp[6] = f2h(v1.z); tmp[7] = f2h(v1.w);
    }
    unsigned int u0 = (unsigned)tmp[0] | ((unsigned)tmp[1] << 16);
    unsigned int u1 = (unsigned)tmp[2] | ((unsigned)tmp[3] << 16);
    unsigned int u2 = (unsigned)tmp[4] | ((unsigned)tmp[5] << 16);
    unsigned int u3 = (unsigned)tmp[6] | ((unsigned)tmp[7] << 16);
    *(uint4*)(sB + (size_t)nr * 520 + o) = make_uint4(u0, u1, u2, u3);
  }
  __syncthreads();

  const int wid = tid >> 6, lane = tid & 63, nl = lane & 15, q = lane >> 4;
  f32x4 acc[2];
  acc[0] = (f32x4){0.f, 0.f, 0.f, 0.f};
  acc[1] = (f32x4){0.f, 0.f, 0.f, 0.f};
  int arow[2];
#pragma unroll
  for (int i = 0; i < 2; ++i) arow[i] = (mb * 8 + wid * 2 + i) * 512 + lane * 8;
  const int bofs = nl * 520 + q * 8;

  f16x8 A[4][2], Bv[2];
#pragma unroll
  for (int s = 0; s < 4; ++s)
#pragma unroll
    for (int i = 0; i < 2; ++i) A[s][i] = *(const f16x8*)(wn + arow[i] + (size_t)s * 16384);
#pragma unroll
  for (int s = 0; s < 2; ++s) Bv[s] = *(const f16x8*)(sB + bofs + s * 32);
#pragma unroll
  for (int s = 0; s < 16; ++s) {
    const int sa = s & 3, sb = s & 1;
    acc[0] = __builtin_amdgcn_mfma_f32_16x16x32_f16(A[sa][0], Bv[sb], acc[0], 0, 0, 0);
    acc[1] = __builtin_amdgcn_mfma_f32_16x16x32_f16(A[sa][1], Bv[sb], acc[1], 0, 0, 0);
    if (s + 4 < 16) {
#pragma unroll
      for (int i = 0; i < 2; ++i) A[sa][i] = *(const f16x8*)(wn + arow[i] + (size_t)(s + 4) * 16384);
    }
    if (s + 2 < 16) Bv[sb] = *(const f16x8*)(sB + bofs + (s + 2) * 32);
  }

  const int n = n0 + nl;
  if (li < 7) {
    if (n < N) {
      const int b = n >> lnp, kk = n & (npos - 1);
      const int t = 255 - (kk << (li + 1));
      const size_t rowoff = ((size_t)(b * 256 + t)) * 256;
#pragma unroll
      for (int i = 0; i < 2; ++i) {
        const int ch = mb * 64 + (wid * 2 + i) * 8 + q * 2;
        const float z0 = tanhf(acc[i][0]) * (1.f / (1.f + expf(-acc[i][1])));
        const float z1 = tanhf(acc[i][2]) * (1.f / (1.f + expf(-acc[i][3])));
        float2 hv = *(const float2*)(hsrc + rowoff + ch);
        *(float2*)(hdst + rowoff + ch) = make_float2(hv.x + z0, hv.y + z1);
        if (kk == 0) {
          float* fp = feats + b * 256 + ch;
          if (li == 0) { fp[0] = z0; fp[1] = z1; }
          else         { fp[0] += z0; fp[1] += z1; }
        }
      }
    }
  } else {
    // li == 7: final layer + fused finalize. 4 blocks (mb), each covers all 8
    // batches (n = nl < 8) and 64 output channels. j partials via LDS + global atomics.
    if (tid < 8) jls[tid] = 0.f;
    __syncthreads();
    if (n < N) {
      const int b = n;                    // lnp == 0, kk == 0, t == 255
      float partial = 0.f;
#pragma unroll
      for (int i = 0; i < 2; ++i) {
        const int ch = mb * 64 + (wid * 2 + i) * 8 + q * 2;
        const float z0 = tanhf(acc[i][0]) * (1.f / (1.f + expf(-acc[i][1])));
        const float z1 = tanhf(acc[i][2]) * (1.f / (1.f + expf(-acc[i][3])));
        const float* fp = feats + b * 256 + ch;
        const float f0 = fp[0] + z0;
        const float f1 = fp[1] + z1;
        *(float2*)(out + b * 256 + ch) = make_float2(f0, f1);
        partial += f0 * jw[ch] + f1 * jw[ch + 1];
      }
      atomicAdd(&jls[b], partial);
    }
    __syncthreads();
    if (tid < 8) atomicAdd(out + NB * 256 + tid, jls[tid]);
  }
}

extern "C" void kernel_launch(void* const* d_in, const int* in_sizes, int n_in,
                              void* d_out, int out_size, void* d_ws, size_t ws_size,
                              hipStream_t stream) {
  const float* x     = (const float*)d_in[0];
  const float* w0    = (const float*)d_in[1];
  const float* w123  = (const float*)d_in[2];
  const float* w4567 = (const float*)d_in[3];
  const float* w8    = (const float*)d_in[4];
  const float* mw    = (const float*)d_in[5];
  const float* gw    = (const float*)d_in[6];
  const float* jw    = (const float*)d_in[7];
  float* out = (float*)d_out;

  float* ws = (float*)d_ws;
  unsigned short* act4g = (unsigned short*)ws;            // 2,097,152 fp16
  float* h0    = ws + 1048576;                            // 524,288 f
  float* h1    = ws + 1572864;                            // 524,288 f
  float* feats = ws + 2097152;                            // 2,048 f
  unsigned short* wp = (unsigned short*)(ws + 2099200);   // 573,440 fp16
  unsigned short* wn = (unsigned short*)(ws + 2385920);   // 2,097,152 fp16

  hipMemsetAsync(out + NB * 256, 0, NB * sizeof(float), stream);  // j accumulator slots
  pack_kernel<<<5216, 512, 0, stream>>>(w123, w4567, w8, mw, gw, wp, wn);
  encoder1<<<1024, 512, 0, stream>>>(x, w0, wp, wp + N1, act4g);
  encoder2<<<256, 512, 0, stream>>>(act4g, wp + N1, wp + N1 + N2, h0);

  float* hs = h0; float* hd = h1;
  for (int i = 0; i < 8; ++i) {
    const unsigned short* wl = wn + (size_t)i * 262144;
    const int N = (128 >> i) * 8;
    const int nN = (N + 15) / 16;
    wnet_kernel<<<4 * nN, 256, 0, stream>>>(wl, hs, hd, feats, jw, out, i);
    float* tmp = hd; hd = hs; hs = tmp;
  }
}